// Round 1
// baseline (758.090 us; speedup 1.0000x reference)
//
#include <hip/hip_runtime.h>
#include <math.h>

#define EPS 1e-5f

// ---------------------------------------------------------------------------
// Problem dims (fixed by the reference):
//   B=8, Cf=512, Cg=256, HID=Co=256, H=W=64, NP=4096 per batch, M=32768 rows.
// All activations held in ws as row-major [row=gm][chan].
// LN folded into GEMM:  q[p,n] = rs_p*(S[p,n] - m_p*colsum[n]) + const[n],
// with S a plain GEMM on raw e_f and W' = diag(ln_g) @ W precomputed on device.
// ---------------------------------------------------------------------------

// ---------------- prep: build canonical K x N weight matrices ----------------
__global__ __launch_bounds__(256) void prep_weights(
    const float* __restrict__ lnfg, const float* __restrict__ wq,
    const float* __restrict__ efpw,
    const float* __restrict__ lngg, const float* __restrict__ wk,
    const float* __restrict__ wv, const float* __restrict__ outcw,
    float* __restrict__ Wb1, float* __restrict__ Wb2, float* __restrict__ Woutc)
{
    int idx = blockIdx.x * 256 + threadIdx.x;
    if (idx < 262144) {                       // Wb1: 512 x 512 (cols 0-255 q, 256-511 efp^T)
        int k = idx >> 9, n = idx & 511;
        Wb1[idx] = (n < 256) ? lnfg[k] * wq[k * 256 + n]
                             : efpw[(size_t)(n - 256) * 512 + k];
    } else if (idx < 262144 + 131072) {       // Wb2: 256 x 512 (k | v)
        int j = idx - 262144;
        int k = j >> 9, n = j & 511;
        Wb2[j] = (n < 256) ? lngg[k] * wk[k * 256 + n]
                           : lngg[k] * wv[k * 256 + (n - 256)];
    } else if (idx < 262144 + 131072 + 65536) { // Woutc = outc_w^T : 256 x 256
        int j = idx - 393216;
        int k = j >> 8, n = j & 255;
        Woutc[j] = outcw[n * 256 + k];
    }
}

__global__ __launch_bounds__(256) void prep_cols(
    const float* __restrict__ lnfg, const float* __restrict__ lnfb,
    const float* __restrict__ wq, const float* __restrict__ bq,
    const float* __restrict__ efpb,
    const float* __restrict__ lngg, const float* __restrict__ lngb,
    const float* __restrict__ wk, const float* __restrict__ bk,
    const float* __restrict__ wv, const float* __restrict__ bv,
    const float* __restrict__ outcb, const float* __restrict__ bng,
    const float* __restrict__ bnb, const float* __restrict__ bnm,
    const float* __restrict__ bnv,
    float* __restrict__ cs1, float* __restrict__ cst1,
    float* __restrict__ cs2, float* __restrict__ cst2,
    float* __restrict__ scv, float* __restrict__ shv)
{
    int idx = blockIdx.x * 256 + threadIdx.x;
    if (idx < 256) {                          // q columns
        int n = idx; float cs = 0.f, ct = 0.f;
        for (int k = 0; k < 512; k++) {
            float w = wq[k * 256 + n];
            cs += lnfg[k] * w; ct += lnfb[k] * w;
        }
        cs1[n] = cs; cst1[n] = ct + bq[n];
    } else if (idx < 512) {                   // efp columns: plain bias
        cs1[idx] = 0.f; cst1[idx] = efpb[idx - 256];
    } else if (idx < 768) {                   // k columns
        int n = idx - 512; float cs = 0.f, ct = 0.f;
        for (int k = 0; k < 256; k++) {
            float w = wk[k * 256 + n];
            cs += lngg[k] * w; ct += lngb[k] * w;
        }
        cs2[n] = cs; cst2[n] = ct + bk[n];
    } else if (idx < 1024) {                  // v columns
        int n = idx - 768; float cs = 0.f, ct = 0.f;
        for (int k = 0; k < 256; k++) {
            float w = wv[k * 256 + n];
            cs += lngg[k] * w; ct += lngb[k] * w;
        }
        cs2[256 + n] = cs; cst2[256 + n] = ct + bv[n];
    } else if (idx < 1280) {                  // BN fold (+ outc bias)
        int n = idx - 1024;
        float s = bng[n] * rsqrtf(bnv[n] + EPS);
        scv[n] = s;
        shv[n] = (outcb[n] - bnm[n]) * s + bnb[n];
    }
}

// ---------------- per-position LN stats (coalesced: lane = position) --------
__global__ __launch_bounds__(256) void ln_stats(
    const float* __restrict__ ef, const float* __restrict__ eg,
    float* __restrict__ mf, float* __restrict__ rf,
    float* __restrict__ mg, float* __restrict__ rg)
{
    int gp = blockIdx.x * 256 + threadIdx.x;   // 0..32767
    int b = gp >> 12, p = gp & 4095;
    if (blockIdx.y == 0) {
        const float* base = ef + (size_t)b * 512 * 4096 + p;
        float s = 0.f, ss = 0.f;
#pragma unroll 8
        for (int c = 0; c < 512; c++) {
            float x = base[(size_t)c * 4096];
            s += x; ss += x * x;
        }
        float m = s * (1.f / 512.f);
        float v = ss * (1.f / 512.f) - m * m;
        mf[gp] = m; rf[gp] = rsqrtf(v + EPS);
    } else {
        const float* base = eg + (size_t)b * 256 * 4096 + p;
        float s = 0.f, ss = 0.f;
#pragma unroll 8
        for (int c = 0; c < 256; c++) {
            float x = base[(size_t)c * 4096];
            s += x; ss += x * x;
        }
        float m = s * (1.f / 256.f);
        float v = ss * (1.f / 256.f) - m * m;
        mg[gp] = m; rg[gp] = rsqrtf(v + EPS);
    }
}

// ---------------- shared fp32 GEMM core: 64x64 tile, KT=16, 4x4/thread ------
// A either K-major (lda = 4096, raw e_f/e_g) or M-major row-major (lda = K).
// LDS tiles padded to 68 -> worst conflict 2-way (free).
template<int K, int LDA, bool AKM>
__device__ __forceinline__ void gemm_core(
    const float* __restrict__ A, const float* __restrict__ Bm, int ldb,
    int m0, int n0, float acc[4][4],
    float* __restrict__ As, float* __restrict__ Bs)
{
    const int tid = threadIdx.x;
    const int tx = tid & 15, ty = tid >> 4;
#pragma unroll
    for (int i = 0; i < 4; i++)
#pragma unroll
        for (int j = 0; j < 4; j++) acc[i][j] = 0.f;

    for (int k0 = 0; k0 < K; k0 += 16) {
        if (AKM) {
#pragma unroll
            for (int i = 0; i < 4; i++) {
                int k = (tid >> 6) + i * 4;
                int m = tid & 63;
                As[k * 68 + m] = A[(size_t)(k0 + k) * LDA + (m0 + m)];
            }
        } else {
#pragma unroll
            for (int i = 0; i < 4; i++) {
                int idx = tid + i * 256;
                int m = idx >> 4, k = idx & 15;
                As[k * 68 + m] = A[(size_t)(m0 + m) * LDA + (k0 + k)];
            }
        }
#pragma unroll
        for (int i = 0; i < 4; i++) {
            int k = (tid >> 6) + i * 4;
            int n = tid & 63;
            Bs[k * 68 + n] = Bm[(size_t)(k0 + k) * ldb + (n0 + n)];
        }
        __syncthreads();
#pragma unroll
        for (int k = 0; k < 16; k++) {
            float4 av = *(const float4*)&As[k * 68 + ty * 4];
            float4 bv = *(const float4*)&Bs[k * 68 + tx * 4];
            float a4[4] = {av.x, av.y, av.z, av.w};
            float b4[4] = {bv.x, bv.y, bv.z, bv.w};
#pragma unroll
            for (int i = 0; i < 4; i++)
#pragma unroll
                for (int j = 0; j < 4; j++)
                    acc[i][j] = fmaf(a4[i], b4[j], acc[i][j]);
        }
        __syncthreads();
    }
}

// ---------------- GEMM1: e_f -> q (LN-affine) and efp --------------------
__global__ __launch_bounds__(256) void gemm1_qefp(
    const float* __restrict__ ef, const float* __restrict__ Wb1,
    const float* __restrict__ cs1, const float* __restrict__ cst1,
    const float* __restrict__ mf, const float* __restrict__ rf,
    float* __restrict__ qbuf, float* __restrict__ efpbuf)
{
    __shared__ float As[16 * 68], Bs[16 * 68];
    int b = blockIdx.z;
    int m0 = blockIdx.x * 64;
    int n0 = blockIdx.y * 64;
    float acc[4][4];
    gemm_core<512, 4096, true>(ef + (size_t)b * 512 * 4096, Wb1, 512, m0, n0, acc, As, Bs);
    int tx = threadIdx.x & 15, ty = threadIdx.x >> 4;
    int nb = n0 + tx * 4;
    if (n0 < 256) {
        float4 cs = *(const float4*)&cs1[nb];
        float4 ct = *(const float4*)&cst1[nb];
#pragma unroll
        for (int i = 0; i < 4; i++) {
            int gm = b * 4096 + m0 + ty * 4 + i;
            float mean = mf[gm], rs = rf[gm];
            float4 o;
            o.x = rs * (acc[i][0] - mean * cs.x) + ct.x;
            o.y = rs * (acc[i][1] - mean * cs.y) + ct.y;
            o.z = rs * (acc[i][2] - mean * cs.z) + ct.z;
            o.w = rs * (acc[i][3] - mean * cs.w) + ct.w;
            *(float4*)&qbuf[(size_t)gm * 256 + nb] = o;
        }
    } else {
        float4 ct = *(const float4*)&cst1[nb];
#pragma unroll
        for (int i = 0; i < 4; i++) {
            int gm = b * 4096 + m0 + ty * 4 + i;
            float4 o = {acc[i][0] + ct.x, acc[i][1] + ct.y,
                        acc[i][2] + ct.z, acc[i][3] + ct.w};
            *(float4*)&efpbuf[(size_t)gm * 256 + (nb - 256)] = o;
        }
    }
}

// ---------------- GEMM2: e_g -> k_full | v_full (both LN-affine) ------------
__global__ __launch_bounds__(256) void gemm2_kv(
    const float* __restrict__ eg, const float* __restrict__ Wb2,
    const float* __restrict__ cs2, const float* __restrict__ cst2,
    const float* __restrict__ mg, const float* __restrict__ rg,
    float* __restrict__ kfull, float* __restrict__ vfull)
{
    __shared__ float As[16 * 68], Bs[16 * 68];
    int b = blockIdx.z;
    int m0 = blockIdx.x * 64;
    int n0 = blockIdx.y * 64;
    float acc[4][4];
    gemm_core<256, 4096, true>(eg + (size_t)b * 256 * 4096, Wb2, 512, m0, n0, acc, As, Bs);
    int tx = threadIdx.x & 15, ty = threadIdx.x >> 4;
    int nb = n0 + tx * 4;
    float4 cs = *(const float4*)&cs2[nb];
    float4 ct = *(const float4*)&cst2[nb];
    float* dst = (n0 < 256) ? kfull : vfull;
    int nw = (n0 < 256) ? nb : nb - 256;
#pragma unroll
    for (int i = 0; i < 4; i++) {
        int gm = b * 4096 + m0 + ty * 4 + i;
        float mean = mg[gm], rs = rg[gm];
        float4 o;
        o.x = rs * (acc[i][0] - mean * cs.x) + ct.x;
        o.y = rs * (acc[i][1] - mean * cs.y) + ct.y;
        o.z = rs * (acc[i][2] - mean * cs.z) + ct.z;
        o.w = rs * (acc[i][3] - mean * cs.w) + ct.w;
        *(float4*)&dst[(size_t)gm * 256 + nw] = o;
    }
}

// ---------------- 16x16 pooling (two-pass, deterministic) -------------------
__global__ __launch_bounds__(256) void pool_pass1(
    const float* __restrict__ kfull, const float* __restrict__ vfull,
    float* __restrict__ kpart, float* __restrict__ vpart)
{
    int blk = blockIdx.x;                 // (b, cell, i-row)
    int i = blk & 15, cell = (blk >> 4) & 15, b = blk >> 8;
    int hp = cell >> 2, wp = cell & 3;
    int o = threadIdx.x;
    int h = hp * 16 + i;
    float mx = -3.402823466e38f, sm = 0.f;
#pragma unroll 4
    for (int j = 0; j < 16; j++) {
        int p = h * 64 + wp * 16 + j;
        size_t base = ((size_t)(b * 4096 + p)) * 256 + o;
        mx = fmaxf(mx, kfull[base]);
        sm += vfull[base];
    }
    kpart[(size_t)blk * 256 + o] = mx;
    vpart[(size_t)blk * 256 + o] = sm;
}

__global__ __launch_bounds__(256) void pool_pass2(
    const float* __restrict__ kpart, const float* __restrict__ vpart,
    float* __restrict__ kp, float* __restrict__ vp)
{
    int blk = blockIdx.x;                 // b*16 + cell
    int o = threadIdx.x;
    float mx = -3.402823466e38f, sm = 0.f;
#pragma unroll 4
    for (int i = 0; i < 16; i++) {
        mx = fmaxf(mx, kpart[((size_t)blk * 16 + i) * 256 + o]);
        sm += vpart[((size_t)blk * 16 + i) * 256 + o];
    }
    kp[(size_t)blk * 256 + o] = mx;
    vp[(size_t)blk * 256 + o] = sm * (1.f / 256.f);
}

// ------- attention (16 keys) + depthwise 3x3 conv -> combined ---------------
// Block = 256 thr handles 16 consecutive positions (same b, same h row).
__global__ __launch_bounds__(256) void attn_dw(
    const float* __restrict__ qbuf, const float* __restrict__ kp,
    const float* __restrict__ vp, const float* __restrict__ dwk,
    float* __restrict__ combined)
{
    __shared__ float qs[16 * 260];    // padded: scalar reads 2-way max
    __shared__ float kps[16 * 260];
    __shared__ float vps[16 * 256];   // float4 reads, lane-consecutive
    __shared__ float attns[16 * 16];
    __shared__ float dwt[9 * 256];    // transposed taps
    int t = threadIdx.x;
    int gm0 = blockIdx.x * 16;
    int b = gm0 >> 12;
    int p0 = gm0 & 4095;
    int h = p0 >> 6;
    int w0 = p0 & 63;

    // stage q rows + pooled k/v (batch b) + transposed dw taps
#pragma unroll
    for (int i = 0; i < 4; i++) {
        int idx = t + i * 256;            // float4 index over 16x64
        int pos = idx >> 6, c4 = idx & 63;
        float4 v = *(const float4*)&qbuf[((size_t)(gm0 + pos)) * 256 + c4 * 4];
        *(float4*)&qs[pos * 260 + c4 * 4] = v;
        float4 kv = *(const float4*)&kp[((size_t)(b * 16 + pos)) * 256 + c4 * 4];
        *(float4*)&kps[pos * 260 + c4 * 4] = kv;
        float4 vv = *(const float4*)&vp[((size_t)(b * 16 + pos)) * 256 + c4 * 4];
        *(float4*)&vps[pos * 256 + c4 * 4] = vv;
    }
#pragma unroll
    for (int tap = 0; tap < 9; tap++) dwt[tap * 256 + t] = dwk[t * 9 + tap];
    __syncthreads();

    // scores + softmax: thread -> (pos = t/16, cell = t%16)
    {
        int pos = t >> 4, cell = t & 15;
        const float4* q4 = (const float4*)&qs[pos * 260];
        const float4* k4 = (const float4*)&kps[cell * 260];
        float s = 0.f;
#pragma unroll 8
        for (int k = 0; k < 64; k++) {
            float4 qv = q4[k], kv = k4[k];
            s = fmaf(qv.x, kv.x, s); s = fmaf(qv.y, kv.y, s);
            s = fmaf(qv.z, kv.z, s); s = fmaf(qv.w, kv.w, s);
        }
        s *= 0.0625f;                       // HID^-0.5 = 1/16
        float mx = s;
#pragma unroll
        for (int off = 8; off >= 1; off >>= 1) mx = fmaxf(mx, __shfl_xor(mx, off));
        float e = __expf(s - mx);
        float sum = e;
#pragma unroll
        for (int off = 8; off >= 1; off >>= 1) sum += __shfl_xor(sum, off);
        attns[pos * 16 + cell] = e / sum;
    }
    __syncthreads();

    // a_i + depthwise conv; wave -> one position per pass, lane -> 4 channels
    int lane = t & 63, wave = t >> 6;
    int o4 = lane * 4;
    float4 kreg[9];
#pragma unroll
    for (int tap = 0; tap < 9; tap++) kreg[tap] = *(const float4*)&dwt[tap * 256 + o4];

    for (int pass = 0; pass < 4; pass++) {
        int pos = pass * 4 + wave;
        int gm = gm0 + pos;
        int ww = w0 + pos;
        float4 acc = {0.f, 0.f, 0.f, 0.f};
#pragma unroll
        for (int c = 0; c < 16; c++) {
            float a = attns[pos * 16 + c];
            float4 v = *(const float4*)&vps[c * 256 + o4];
            acc.x = fmaf(a, v.x, acc.x); acc.y = fmaf(a, v.y, acc.y);
            acc.z = fmaf(a, v.z, acc.z); acc.w = fmaf(a, v.w, acc.w);
        }
#pragma unroll
        for (int dy = 0; dy < 3; dy++) {
            int hh = h + dy - 1;
            if (hh < 0 || hh > 63) continue;
#pragma unroll
            for (int dx = 0; dx < 3; dx++) {
                int xx = ww + dx - 1;
                if (xx < 0 || xx > 63) continue;
                int gn = b * 4096 + hh * 64 + xx;
                float4 qv = *(const float4*)&qbuf[(size_t)gn * 256 + o4];
                float4 kk = kreg[dy * 3 + dx];
                acc.x = fmaf(qv.x, kk.x, acc.x); acc.y = fmaf(qv.y, kk.y, acc.y);
                acc.z = fmaf(qv.z, kk.z, acc.z); acc.w = fmaf(qv.w, kk.w, acc.w);
            }
        }
        *(float4*)&combined[(size_t)gm * 256 + o4] = acc;
    }
}

// ---------------- GEMM3: combined @ wo + bo, gate by efp -> ea --------------
__global__ __launch_bounds__(256) void gemm3_comb(
    const float* __restrict__ combined, const float* __restrict__ wo,
    const float* __restrict__ bo, const float* __restrict__ efp,
    float* __restrict__ ea)
{
    __shared__ float As[16 * 68], Bs[16 * 68];
    int gm0 = blockIdx.x * 64;
    int n0 = blockIdx.y * 64;
    float acc[4][4];
    gemm_core<256, 256, false>(combined, wo, 256, gm0, n0, acc, As, Bs);
    int tx = threadIdx.x & 15, ty = threadIdx.x >> 4;
    int nb = n0 + tx * 4;
    float4 bv = *(const float4*)&bo[nb];
#pragma unroll
    for (int i = 0; i < 4; i++) {
        int gm = gm0 + ty * 4 + i;
        float4 e = *(const float4*)&efp[(size_t)gm * 256 + nb];
        float4 o;
        o.x = (acc[i][0] + bv.x) * e.x;
        o.y = (acc[i][1] + bv.y) * e.y;
        o.z = (acc[i][2] + bv.z) * e.z;
        o.w = (acc[i][3] + bv.w) * e.w;
        *(float4*)&ea[(size_t)gm * 256 + nb] = o;
    }
}

// ---------------- GEMM4: ea @ outc^T, BN + ReLU, NCHW transposed store ------
__global__ __launch_bounds__(256) void gemm4_out(
    const float* __restrict__ ea, const float* __restrict__ Woutc,
    const float* __restrict__ scv, const float* __restrict__ shv,
    float* __restrict__ outp)
{
    __shared__ float smem[4288];   // max(2*1088 staging, 64*65 transpose tile)
    float* As = smem;
    float* Bs = smem + 1088;
    int gm0 = blockIdx.x * 64, n0 = blockIdx.y * 64;
    float acc[4][4];
    gemm_core<256, 256, false>(ea, Woutc, 256, gm0, n0, acc, As, Bs);
    int tx = threadIdx.x & 15, ty = threadIdx.x >> 4;
    float* tile = smem;            // safe: core ends with __syncthreads()
#pragma unroll
    for (int j = 0; j < 4; j++) {
        int n = n0 + tx * 4 + j;
        float s = scv[n], hh = shv[n];
#pragma unroll
        for (int i = 0; i < 4; i++) {
            float v = fmaf(acc[i][j], s, hh);
            tile[(tx * 4 + j) * 65 + ty * 4 + i] = fmaxf(v, 0.f);
        }
    }
    __syncthreads();
    int b = gm0 >> 12, p0 = gm0 & 4095;
    int lane = threadIdx.x & 63, grp = threadIdx.x >> 6;
    size_t obase = (size_t)b * 256 * 4096 + p0 + lane;
#pragma unroll
    for (int r = 0; r < 16; r++) {
        int nl = grp * 16 + r;
        outp[obase + (size_t)(n0 + nl) * 4096] = tile[nl * 65 + lane];
    }
}

// ---------------------------------------------------------------------------
extern "C" void kernel_launch(void* const* d_in, const int* in_sizes, int n_in,
                              void* d_out, int out_size, void* d_ws, size_t ws_size,
                              hipStream_t stream)
{
    const float* e_f   = (const float*)d_in[0];
    const float* e_g   = (const float*)d_in[1];
    // d_in[2] l_feat, d_in[3] l_mask: unused by the reference
    const float* lnfg  = (const float*)d_in[4];
    const float* lnfb  = (const float*)d_in[5];
    const float* lngg  = (const float*)d_in[6];
    const float* lngb  = (const float*)d_in[7];
    const float* wq    = (const float*)d_in[8];
    const float* bq    = (const float*)d_in[9];
    const float* wk    = (const float*)d_in[10];
    const float* bk    = (const float*)d_in[11];
    const float* wv    = (const float*)d_in[12];
    const float* bv    = (const float*)d_in[13];
    const float* wo    = (const float*)d_in[14];
    const float* bo    = (const float*)d_in[15];
    const float* dwk   = (const float*)d_in[16];
    const float* efpw  = (const float*)d_in[17];
    const float* efpb  = (const float*)d_in[18];
    const float* outcw = (const float*)d_in[19];
    const float* outcb = (const float*)d_in[20];
    const float* bng   = (const float*)d_in[21];
    const float* bnb   = (const float*)d_in[22];
    const float* bnm   = (const float*)d_in[23];
    const float* bnv   = (const float*)d_in[24];
    float* outp = (float*)d_out;

    float* p = (float*)d_ws;
    float* mf    = p; p += 32768;
    float* rf    = p; p += 32768;
    float* mg    = p; p += 32768;
    float* rg    = p; p += 32768;
    float* Wb1   = p; p += 512 * 512;
    float* cs1   = p; p += 512;
    float* cst1  = p; p += 512;
    float* Wb2   = p; p += 256 * 512;
    float* cs2   = p; p += 512;
    float* cst2  = p; p += 512;
    float* Woutc = p; p += 256 * 256;
    float* scv   = p; p += 256;
    float* shv   = p; p += 256;
    float* qbuf   = p; p += (size_t)32768 * 256;
    float* efpbuf = p; p += (size_t)32768 * 256;
    float* kfull  = p; p += (size_t)32768 * 256;   // reused as `combined`
    float* vfull  = p; p += (size_t)32768 * 256;   // reused as `ea`
    float* kpart  = p; p += 2048 * 256;
    float* vpart  = p; p += 2048 * 256;
    float* kp     = p; p += 8 * 16 * 256;
    float* vp     = p; p += 8 * 16 * 256;

    prep_weights<<<1792, 256, 0, stream>>>(lnfg, wq, efpw, lngg, wk, wv, outcw,
                                           Wb1, Wb2, Woutc);
    prep_cols<<<5, 256, 0, stream>>>(lnfg, lnfb, wq, bq, efpb,
                                     lngg, lngb, wk, bk, wv, bv,
                                     outcb, bng, bnb, bnm, bnv,
                                     cs1, cst1, cs2, cst2, scv, shv);
    ln_stats<<<dim3(128, 2), 256, 0, stream>>>(e_f, e_g, mf, rf, mg, rg);
    gemm1_qefp<<<dim3(64, 8, 8), 256, 0, stream>>>(e_f, Wb1, cs1, cst1, mf, rf,
                                                   qbuf, efpbuf);
    gemm2_kv<<<dim3(64, 8, 8), 256, 0, stream>>>(e_g, Wb2, cs2, cst2, mg, rg,
                                                 kfull, vfull);
    pool_pass1<<<2048, 256, 0, stream>>>(kfull, vfull, kpart, vpart);
    pool_pass2<<<128, 256, 0, stream>>>(kpart, vpart, kp, vp);
    attn_dw<<<2048, 256, 0, stream>>>(qbuf, kp, vp, dwk, /*combined=*/kfull);
    gemm3_comb<<<dim3(512, 4), 256, 0, stream>>>(/*combined=*/kfull, wo, bo,
                                                 efpbuf, /*ea=*/vfull);
    gemm4_out<<<dim3(512, 4), 256, 0, stream>>>(/*ea=*/vfull, Woutc, scv, shv, outp);
}

// Round 2
// 404.437 us; speedup vs baseline: 1.8744x; 1.8744x over previous
//
#include <hip/hip_runtime.h>
#include <math.h>

#define EPS 1e-5f

typedef __attribute__((ext_vector_type(8))) short bf16x8;
typedef __attribute__((ext_vector_type(4))) float f32x4;

__device__ __forceinline__ unsigned short f2bf(float f) {
    unsigned int u = __float_as_uint(f);
    u += 0x7fff + ((u >> 16) & 1);            // round-to-nearest-even
    return (unsigned short)(u >> 16);
}
__device__ __forceinline__ float bf2f(unsigned short h) {
    return __uint_as_float(((unsigned int)h) << 16);
}
__device__ __forceinline__ void async16(void* lds, const void* g) {
    __builtin_amdgcn_global_load_lds(
        (const __attribute__((address_space(1))) unsigned int*)g,
        (__attribute__((address_space(3))) unsigned int*)lds, 16, 0, 0);
}

// ---------------- prep: bf16 weight matrices in [N][K] (B-operand) layout ---
__global__ __launch_bounds__(256) void prep_weights_bf(
    const float* __restrict__ lnfg, const float* __restrict__ wq,
    const float* __restrict__ efpw,
    const float* __restrict__ lngg, const float* __restrict__ wk,
    const float* __restrict__ wv, const float* __restrict__ wo,
    const float* __restrict__ outcw,
    unsigned short* __restrict__ Wb1t, unsigned short* __restrict__ Wb2t,
    unsigned short* __restrict__ Wot, unsigned short* __restrict__ Woc)
{
    int idx = blockIdx.x * 256 + threadIdx.x;
    if (idx < 262144) {                       // Wb1t [n=512][k=512]: q | efp
        int n = idx >> 9, k = idx & 511;
        float v = (n < 256) ? lnfg[k] * wq[k * 256 + n]
                            : efpw[(size_t)(n - 256) * 512 + k];
        Wb1t[idx] = f2bf(v);
    } else if (idx < 393216) {                // Wb2t [n=512][k=256]: k | v
        int j = idx - 262144; int n = j >> 8, k = j & 255;
        float v = (n < 256) ? lngg[k] * wk[k * 256 + n]
                            : lngg[k] * wv[k * 256 + (n - 256)];
        Wb2t[j] = f2bf(v);
    } else if (idx < 458752) {                // Wot [256][256] = wo^T
        int j = idx - 393216; int n = j >> 8, k = j & 255;
        Wot[j] = f2bf(wo[k * 256 + n]);
    } else if (idx < 524288) {                // Woc [256][256] = outc_w (already [n][k])
        int j = idx - 458752;
        Woc[j] = f2bf(outcw[j]);
    }
}

// ---------------- fp32 column constants (LN folding) ------------------------
__global__ __launch_bounds__(256) void prep_cols(
    const float* __restrict__ lnfg, const float* __restrict__ lnfb,
    const float* __restrict__ wq, const float* __restrict__ bq,
    const float* __restrict__ efpb,
    const float* __restrict__ lngg, const float* __restrict__ lngb,
    const float* __restrict__ wk, const float* __restrict__ bk,
    const float* __restrict__ wv, const float* __restrict__ bv,
    const float* __restrict__ outcb, const float* __restrict__ bng,
    const float* __restrict__ bnb, const float* __restrict__ bnm,
    const float* __restrict__ bnv,
    float* __restrict__ cs1, float* __restrict__ cst1,
    float* __restrict__ cs2, float* __restrict__ cst2,
    float* __restrict__ scv, float* __restrict__ shv)
{
    int idx = blockIdx.x * 256 + threadIdx.x;
    if (idx < 256) {
        int n = idx; float cs = 0.f, ct = 0.f;
        for (int k = 0; k < 512; k++) {
            float w = wq[k * 256 + n];
            cs += lnfg[k] * w; ct += lnfb[k] * w;
        }
        cs1[n] = cs; cst1[n] = ct + bq[n];
    } else if (idx < 512) {
        cs1[idx] = 0.f; cst1[idx] = efpb[idx - 256];
    } else if (idx < 768) {
        int n = idx - 512; float cs = 0.f, ct = 0.f;
        for (int k = 0; k < 256; k++) {
            float w = wk[k * 256 + n];
            cs += lngg[k] * w; ct += lngb[k] * w;
        }
        cs2[n] = cs; cst2[n] = ct + bk[n];
    } else if (idx < 1024) {
        int n = idx - 768; float cs = 0.f, ct = 0.f;
        for (int k = 0; k < 256; k++) {
            float w = wv[k * 256 + n];
            cs += lngg[k] * w; ct += lngb[k] * w;
        }
        cs2[256 + n] = cs; cst2[256 + n] = ct + bv[n];
    } else if (idx < 1280) {
        int n = idx - 1024;
        float s = bng[n] * rsqrtf(bnv[n] + EPS);
        scv[n] = s;
        shv[n] = (outcb[n] - bnm[n]) * s + bnb[n];
    }
}

// ---------------- LN stats on raw fp32 inputs -------------------------------
__global__ __launch_bounds__(256) void ln_stats(
    const float* __restrict__ ef, const float* __restrict__ eg,
    float* __restrict__ mf, float* __restrict__ rf,
    float* __restrict__ mg, float* __restrict__ rg)
{
    int gp = blockIdx.x * 256 + threadIdx.x;
    int b = gp >> 12, p = gp & 4095;
    if (blockIdx.y == 0) {
        const float* base = ef + (size_t)b * 512 * 4096 + p;
        float s = 0.f, ss = 0.f;
#pragma unroll 8
        for (int c = 0; c < 512; c++) {
            float x = base[(size_t)c * 4096];
            s += x; ss += x * x;
        }
        float m = s * (1.f / 512.f);
        float v = ss * (1.f / 512.f) - m * m;
        mf[gp] = m; rf[gp] = rsqrtf(v + EPS);
    } else {
        const float* base = eg + (size_t)b * 256 * 4096 + p;
        float s = 0.f, ss = 0.f;
#pragma unroll 8
        for (int c = 0; c < 256; c++) {
            float x = base[(size_t)c * 4096];
            s += x; ss += x * x;
        }
        float m = s * (1.f / 256.f);
        float v = ss * (1.f / 256.f) - m * m;
        mg[gp] = m; rg[gp] = rsqrtf(v + EPS);
    }
}

// ---------------- NCHW fp32 -> [M][C] bf16 transpose ------------------------
__global__ __launch_bounds__(256) void transpose_cvt(
    const float* __restrict__ src, unsigned short* __restrict__ dst, int C)
{
    __shared__ float tile[64][65];
    int b = blockIdx.z, c0 = blockIdx.y * 64, p0 = blockIdx.x * 64;
    const float* s = src + ((size_t)b * C + c0) * 4096 + p0;
    int t = threadIdx.x;
#pragma unroll
    for (int i = 0; i < 16; i++) {
        int c = i * 4 + (t >> 6);
        tile[c][t & 63] = s[(size_t)c * 4096 + (t & 63)];
    }
    __syncthreads();
    unsigned short* d = dst + ((size_t)(b * 4096 + p0)) * C + c0;
#pragma unroll
    for (int i = 0; i < 16; i++) {
        int p = i * 4 + (t >> 6);
        d[(size_t)p * C + (t & 63)] = f2bf(tile[t & 63][p]);
    }
}

// ---------------- MFMA GEMM core --------------------------------------------
// A [M][K] bf16 row-major, Bt [N][K] bf16 row-major. 128x128 C-tile,
// 4 waves in 2x2, each wave 4x4 tiles of 16x16x32. BK=64.
// LDS layout [row][8 granules of 16B], granule XOR-swizzled by row&7 so both
// the global_load_lds staging (wave-uniform base + lane*16) and the
// ds_read_b128 fragment reads are conflict-free (2-way max).
template<int K>
__device__ __forceinline__ void mfma_core(
    const unsigned short* __restrict__ A, const unsigned short* __restrict__ Bt,
    int m0, int n0, unsigned short* As, unsigned short* Bs, f32x4 acc[4][4])
{
    const int tid = threadIdx.x;
    const int wave = tid >> 6, lane = tid & 63;
    const int wm = (wave & 1) * 64, wn = (wave >> 1) * 64;
#pragma unroll
    for (int i = 0; i < 4; i++)
#pragma unroll
        for (int j = 0; j < 4; j++) acc[i][j] = (f32x4){0.f, 0.f, 0.f, 0.f};

    const int srow = wave * 32 + (lane >> 3);          // row within 128-tile
    const int sg = (lane & 7) ^ ((lane >> 3) & 7);     // swizzled global granule
    const unsigned short* ga = A + (size_t)(m0 + srow) * K + sg * 8;
    const unsigned short* gb = Bt + (size_t)(n0 + srow) * K + sg * 8;

    for (int k0 = 0; k0 < K; k0 += 64) {
#pragma unroll
        for (int t = 0; t < 4; t++) {
            async16(As + (wave * 32 + t * 8) * 64, ga + (size_t)t * 8 * K + k0);
            async16(Bs + (wave * 32 + t * 8) * 64, gb + (size_t)t * 8 * K + k0);
        }
        __syncthreads();
#pragma unroll
        for (int ks = 0; ks < 2; ks++) {
            bf16x8 af[4], bfr[4];
            int kb = ks * 4 + (lane >> 4);
            int slot = (kb ^ (lane & 7)) * 8;
#pragma unroll
            for (int i = 0; i < 4; i++) {
                int m = wm + i * 16 + (lane & 15);
                af[i] = *(const bf16x8*)&As[m * 64 + slot];
                int n = wn + i * 16 + (lane & 15);
                bfr[i] = *(const bf16x8*)&Bs[n * 64 + slot];
            }
#pragma unroll
            for (int i = 0; i < 4; i++)
#pragma unroll
                for (int j = 0; j < 4; j++)
                    acc[i][j] = __builtin_amdgcn_mfma_f32_16x16x32_bf16(
                        af[i], bfr[j], acc[i][j], 0, 0, 0);
        }
        __syncthreads();
    }
}

// ---------------- GEMM1: ef_bf x Wb1t -> q (bf16, LN affine) | efp (fp32) ---
__global__ __launch_bounds__(256) void gemm1_mfma(
    const unsigned short* __restrict__ ef_bf, const unsigned short* __restrict__ Wb1t,
    const float* __restrict__ cs1, const float* __restrict__ cst1,
    const float* __restrict__ mf, const float* __restrict__ rf,
    unsigned short* __restrict__ qbuf, float* __restrict__ efpbuf)
{
    __shared__ unsigned short As[8192], Bs[8192];
    f32x4 acc[4][4];
    int m0 = blockIdx.x * 128, n0 = blockIdx.y * 128;
    mfma_core<512>(ef_bf, Wb1t, m0, n0, As, Bs, acc);
    int lane = threadIdx.x & 63, wave = threadIdx.x >> 6;
    int wm = (wave & 1) * 64, wn = (wave >> 1) * 64;
    bool isq = (n0 < 256);
#pragma unroll
    for (int i = 0; i < 4; i++) {
#pragma unroll
        for (int r = 0; r < 4; r++) {
            int gm = m0 + wm + i * 16 + ((lane >> 4) * 4) + r;
            float mean = mf[gm], rs = rf[gm];
#pragma unroll
            for (int j = 0; j < 4; j++) {
                int n = n0 + wn + j * 16 + (lane & 15);
                float v = acc[i][j][r];
                if (isq) {
                    float o = rs * (v - mean * cs1[n]) + cst1[n];
                    qbuf[(size_t)gm * 256 + n] = f2bf(o);
                } else {
                    efpbuf[(size_t)gm * 256 + (n - 256)] = v + cst1[n];
                }
            }
        }
    }
}

// ---------------- GEMM2: eg_bf x Wb2t -> kfull | vfull (bf16, LN affine) ----
__global__ __launch_bounds__(256) void gemm2_mfma(
    const unsigned short* __restrict__ eg_bf, const unsigned short* __restrict__ Wb2t,
    const float* __restrict__ cs2, const float* __restrict__ cst2,
    const float* __restrict__ mg, const float* __restrict__ rg,
    unsigned short* __restrict__ kfull, unsigned short* __restrict__ vfull)
{
    __shared__ unsigned short As[8192], Bs[8192];
    f32x4 acc[4][4];
    int m0 = blockIdx.x * 128, n0 = blockIdx.y * 128;
    mfma_core<256>(eg_bf, Wb2t, m0, n0, As, Bs, acc);
    int lane = threadIdx.x & 63, wave = threadIdx.x >> 6;
    int wm = (wave & 1) * 64, wn = (wave >> 1) * 64;
    unsigned short* dst = (n0 < 256) ? kfull : vfull;
    int nsub = (n0 < 256) ? 0 : 256;
#pragma unroll
    for (int i = 0; i < 4; i++) {
#pragma unroll
        for (int r = 0; r < 4; r++) {
            int gm = m0 + wm + i * 16 + ((lane >> 4) * 4) + r;
            float mean = mg[gm], rs = rg[gm];
#pragma unroll
            for (int j = 0; j < 4; j++) {
                int n = n0 + wn + j * 16 + (lane & 15);
                float o = rs * (acc[i][j][r] - mean * cs2[n]) + cst2[n];
                dst[(size_t)gm * 256 + (n - nsub)] = f2bf(o);
            }
        }
    }
}

// ---------------- GEMM3: combined x Wot, +bo, gate by efp -> ea (bf16) ------
__global__ __launch_bounds__(256) void gemm3_mfma(
    const unsigned short* __restrict__ comb, const unsigned short* __restrict__ Wot,
    const float* __restrict__ bo, const float* __restrict__ efp,
    unsigned short* __restrict__ ea)
{
    __shared__ unsigned short As[8192], Bs[8192];
    f32x4 acc[4][4];
    int m0 = blockIdx.x * 128, n0 = blockIdx.y * 128;
    mfma_core<256>(comb, Wot, m0, n0, As, Bs, acc);
    int lane = threadIdx.x & 63, wave = threadIdx.x >> 6;
    int wm = (wave & 1) * 64, wn = (wave >> 1) * 64;
#pragma unroll
    for (int i = 0; i < 4; i++) {
#pragma unroll
        for (int r = 0; r < 4; r++) {
            int gm = m0 + wm + i * 16 + ((lane >> 4) * 4) + r;
#pragma unroll
            for (int j = 0; j < 4; j++) {
                int n = n0 + wn + j * 16 + (lane & 15);
                float o = (acc[i][j][r] + bo[n]) * efp[(size_t)gm * 256 + n];
                ea[(size_t)gm * 256 + n] = f2bf(o);
            }
        }
    }
}

// ---------------- GEMM4 (transposed): Woc x ea^T -> out NCHW, BN+ReLU -------
// C rows = out-channel (m), C cols = position (n) -> coalesced NCHW store.
__global__ __launch_bounds__(256) void gemm4_mfma(
    const unsigned short* __restrict__ Woc, const unsigned short* __restrict__ ea,
    const float* __restrict__ scv, const float* __restrict__ shv,
    float* __restrict__ outp)
{
    __shared__ unsigned short As[8192], Bs[8192];
    f32x4 acc[4][4];
    int m0 = blockIdx.x * 128, n0 = blockIdx.y * 128;
    mfma_core<256>(Woc, ea, m0, n0, As, Bs, acc);
    int lane = threadIdx.x & 63, wave = threadIdx.x >> 6;
    int wm = (wave & 1) * 64, wn = (wave >> 1) * 64;
#pragma unroll
    for (int i = 0; i < 4; i++) {
#pragma unroll
        for (int r = 0; r < 4; r++) {
            int co = m0 + wm + i * 16 + ((lane >> 4) * 4) + r;
            float s = scv[co], hh = shv[co];
#pragma unroll
            for (int j = 0; j < 4; j++) {
                int p = n0 + wn + j * 16 + (lane & 15);
                float o = fmaxf(fmaf(acc[i][j][r], s, hh), 0.f);
                outp[((size_t)(p >> 12)) * 1048576 + (size_t)co * 4096 + (p & 4095)] = o;
            }
        }
    }
}

// ---------------- 16x16 pooling (bf16 in, fp32 out) -------------------------
__global__ __launch_bounds__(256) void pool_pass1(
    const unsigned short* __restrict__ kfull, const unsigned short* __restrict__ vfull,
    float* __restrict__ kpart, float* __restrict__ vpart)
{
    int blk = blockIdx.x;
    int i = blk & 15, cell = (blk >> 4) & 15, b = blk >> 8;
    int hp = cell >> 2, wp = cell & 3;
    int o = threadIdx.x;
    int h = hp * 16 + i;
    float mx = -3.402823466e38f, sm = 0.f;
#pragma unroll 4
    for (int j = 0; j < 16; j++) {
        int p = h * 64 + wp * 16 + j;
        size_t base = ((size_t)(b * 4096 + p)) * 256 + o;
        mx = fmaxf(mx, bf2f(kfull[base]));
        sm += bf2f(vfull[base]);
    }
    kpart[(size_t)blk * 256 + o] = mx;
    vpart[(size_t)blk * 256 + o] = sm;
}

__global__ __launch_bounds__(256) void pool_pass2(
    const float* __restrict__ kpart, const float* __restrict__ vpart,
    float* __restrict__ kp, float* __restrict__ vp)
{
    int blk = blockIdx.x;
    int o = threadIdx.x;
    float mx = -3.402823466e38f, sm = 0.f;
#pragma unroll 4
    for (int i = 0; i < 16; i++) {
        mx = fmaxf(mx, kpart[((size_t)blk * 16 + i) * 256 + o]);
        sm += vpart[((size_t)blk * 16 + i) * 256 + o];
    }
    kp[(size_t)blk * 256 + o] = mx;
    vp[(size_t)blk * 256 + o] = sm * (1.f / 256.f);
}

// ---------------- attention (16 keys) + depthwise 3x3 -> combined (bf16) ----
__global__ __launch_bounds__(256) void attn_dw(
    const unsigned short* __restrict__ qbuf, const float* __restrict__ kp,
    const float* __restrict__ vp, const float* __restrict__ dwk,
    unsigned short* __restrict__ combined)
{
    __shared__ float qs[16 * 260];
    __shared__ float kps[16 * 260];
    __shared__ float vps[16 * 256];
    __shared__ float attns[16 * 16];
    __shared__ float dwt[9 * 256];
    int t = threadIdx.x;
    int gm0 = blockIdx.x * 16;
    int b = gm0 >> 12;
    int p0 = gm0 & 4095;
    int h = p0 >> 6;
    int w0 = p0 & 63;

    // stage q (bf16 -> fp32 LDS)
#pragma unroll
    for (int i = 0; i < 2; i++) {
        int idx = t + i * 256;               // 512 granules of 8 bf16
        int pos = idx >> 5, g8 = idx & 31;
        uint4 raw = *(const uint4*)(qbuf + ((size_t)(gm0 + pos)) * 256 + g8 * 8);
        float* q8 = &qs[pos * 260 + g8 * 8];
        q8[0] = __uint_as_float(raw.x << 16); q8[1] = __uint_as_float(raw.x & 0xffff0000u);
        q8[2] = __uint_as_float(raw.y << 16); q8[3] = __uint_as_float(raw.y & 0xffff0000u);
        q8[4] = __uint_as_float(raw.z << 16); q8[5] = __uint_as_float(raw.z & 0xffff0000u);
        q8[6] = __uint_as_float(raw.w << 16); q8[7] = __uint_as_float(raw.w & 0xffff0000u);
    }
#pragma unroll
    for (int i = 0; i < 4; i++) {
        int idx = t + i * 256;
        int pos = idx >> 6, c4 = idx & 63;
        float4 kv = *(const float4*)&kp[((size_t)(b * 16 + pos)) * 256 + c4 * 4];
        *(float4*)&kps[pos * 260 + c4 * 4] = kv;
        float4 vv = *(const float4*)&vp[((size_t)(b * 16 + pos)) * 256 + c4 * 4];
        *(float4*)&vps[pos * 256 + c4 * 4] = vv;
    }
#pragma unroll
    for (int tap = 0; tap < 9; tap++) dwt[tap * 256 + t] = dwk[t * 9 + tap];
    __syncthreads();

    // scores + softmax
    {
        int pos = t >> 4, cell = t & 15;
        const float4* q4 = (const float4*)&qs[pos * 260];
        const float4* k4 = (const float4*)&kps[cell * 260];
        float s = 0.f;
#pragma unroll 8
        for (int k = 0; k < 64; k++) {
            float4 qv = q4[k], kv = k4[k];
            s = fmaf(qv.x, kv.x, s); s = fmaf(qv.y, kv.y, s);
            s = fmaf(qv.z, kv.z, s); s = fmaf(qv.w, kv.w, s);
        }
        s *= 0.0625f;
        float mx = s;
#pragma unroll
        for (int off = 8; off >= 1; off >>= 1) mx = fmaxf(mx, __shfl_xor(mx, off));
        float e = __expf(s - mx);
        float sum = e;
#pragma unroll
        for (int off = 8; off >= 1; off >>= 1) sum += __shfl_xor(sum, off);
        attns[pos * 16 + cell] = e / sum;
    }
    __syncthreads();

    int lane = t & 63, wave = t >> 6;
    int o4 = lane * 4;
    float4 kreg[9];
#pragma unroll
    for (int tap = 0; tap < 9; tap++) kreg[tap] = *(const float4*)&dwt[tap * 256 + o4];

    for (int pass = 0; pass < 4; pass++) {
        int pos = pass * 4 + wave;
        int gm = gm0 + pos;
        int ww = w0 + pos;
        float4 acc = {0.f, 0.f, 0.f, 0.f};
#pragma unroll
        for (int c = 0; c < 16; c++) {
            float a = attns[pos * 16 + c];
            float4 v = *(const float4*)&vps[c * 256 + o4];
            acc.x = fmaf(a, v.x, acc.x); acc.y = fmaf(a, v.y, acc.y);
            acc.z = fmaf(a, v.z, acc.z); acc.w = fmaf(a, v.w, acc.w);
        }
#pragma unroll
        for (int dy = 0; dy < 3; dy++) {
            int hh = h + dy - 1;
            if (hh < 0 || hh > 63) continue;
#pragma unroll
            for (int dx = 0; dx < 3; dx++) {
                int xx = ww + dx - 1;
                if (xx < 0 || xx > 63) continue;
                int gn = b * 4096 + hh * 64 + xx;
                uint2 qb = *(const uint2*)(qbuf + (size_t)gn * 256 + o4);
                float4 qv;
                qv.x = __uint_as_float(qb.x << 16);
                qv.y = __uint_as_float(qb.x & 0xffff0000u);
                qv.z = __uint_as_float(qb.y << 16);
                qv.w = __uint_as_float(qb.y & 0xffff0000u);
                float4 kk = kreg[dy * 3 + dx];
                acc.x = fmaf(qv.x, kk.x, acc.x); acc.y = fmaf(qv.y, kk.y, acc.y);
                acc.z = fmaf(qv.z, kk.z, acc.z); acc.w = fmaf(qv.w, kk.w, acc.w);
            }
        }
        uint2 pk;
        pk.x = ((unsigned int)f2bf(acc.x)) | (((unsigned int)f2bf(acc.y)) << 16);
        pk.y = ((unsigned int)f2bf(acc.z)) | (((unsigned int)f2bf(acc.w)) << 16);
        *(uint2*)(combined + (size_t)gm * 256 + o4) = pk;
    }
}

// ---------------------------------------------------------------------------
extern "C" void kernel_launch(void* const* d_in, const int* in_sizes, int n_in,
                              void* d_out, int out_size, void* d_ws, size_t ws_size,
                              hipStream_t stream)
{
    const float* e_f   = (const float*)d_in[0];
    const float* e_g   = (const float*)d_in[1];
    const float* lnfg  = (const float*)d_in[4];
    const float* lnfb  = (const float*)d_in[5];
    const float* lngg  = (const float*)d_in[6];
    const float* lngb  = (const float*)d_in[7];
    const float* wq    = (const float*)d_in[8];
    const float* bq    = (const float*)d_in[9];
    const float* wk    = (const float*)d_in[10];
    const float* bk    = (const float*)d_in[11];
    const float* wv    = (const float*)d_in[12];
    const float* bv    = (const float*)d_in[13];
    const float* wo    = (const float*)d_in[14];
    const float* bo    = (const float*)d_in[15];
    const float* dwk   = (const float*)d_in[16];
    const float* efpw  = (const float*)d_in[17];
    const float* efpb  = (const float*)d_in[18];
    const float* outcw = (const float*)d_in[19];
    const float* outcb = (const float*)d_in[20];
    const float* bng   = (const float*)d_in[21];
    const float* bnb   = (const float*)d_in[22];
    const float* bnm   = (const float*)d_in[23];
    const float* bnv   = (const float*)d_in[24];
    float* outp = (float*)d_out;

    char* base = (char*)d_ws;
    auto alloc = [&](size_t bytes) -> char* {
        char* r = base; base += (bytes + 255) & ~(size_t)255; return r;
    };
    float* mf    = (float*)alloc(32768 * 4);
    float* rf    = (float*)alloc(32768 * 4);
    float* mg    = (float*)alloc(32768 * 4);
    float* rg    = (float*)alloc(32768 * 4);
    float* cs1   = (float*)alloc(512 * 4);
    float* cst1  = (float*)alloc(512 * 4);
    float* cs2   = (float*)alloc(512 * 4);
    float* cst2  = (float*)alloc(512 * 4);
    float* scv   = (float*)alloc(256 * 4);
    float* shv   = (float*)alloc(256 * 4);
    unsigned short* Wb1t = (unsigned short*)alloc(262144 * 2);
    unsigned short* Wb2t = (unsigned short*)alloc(131072 * 2);
    unsigned short* Wot  = (unsigned short*)alloc(65536 * 2);
    unsigned short* Woc  = (unsigned short*)alloc(65536 * 2);
    unsigned short* ef_bf = (unsigned short*)alloc((size_t)32768 * 512 * 2);
    unsigned short* eg_bf = (unsigned short*)alloc((size_t)32768 * 256 * 2);
    unsigned short* qbuf  = (unsigned short*)alloc((size_t)32768 * 256 * 2);
    float* efpbuf = (float*)alloc((size_t)32768 * 256 * 4);
    unsigned short* kfull = (unsigned short*)alloc((size_t)32768 * 256 * 2); // -> combined
    unsigned short* vfull = (unsigned short*)alloc((size_t)32768 * 256 * 2); // -> ea
    float* kpart = (float*)alloc((size_t)2048 * 256 * 4);
    float* vpart = (float*)alloc((size_t)2048 * 256 * 4);
    float* kp    = (float*)alloc(128 * 256 * 4);
    float* vp    = (float*)alloc(128 * 256 * 4);

    prep_weights_bf<<<2048, 256, 0, stream>>>(lnfg, wq, efpw, lngg, wk, wv, wo,
                                              outcw, Wb1t, Wb2t, Wot, Woc);
    prep_cols<<<5, 256, 0, stream>>>(lnfg, lnfb, wq, bq, efpb,
                                     lngg, lngb, wk, bk, wv, bv,
                                     outcb, bng, bnb, bnm, bnv,
                                     cs1, cst1, cs2, cst2, scv, shv);
    ln_stats<<<dim3(128, 2), 256, 0, stream>>>(e_f, e_g, mf, rf, mg, rg);
    transpose_cvt<<<dim3(64, 8, 8), 256, 0, stream>>>(e_f, ef_bf, 512);
    transpose_cvt<<<dim3(64, 4, 8), 256, 0, stream>>>(e_g, eg_bf, 256);
    gemm1_mfma<<<dim3(256, 4), 256, 0, stream>>>(ef_bf, Wb1t, cs1, cst1, mf, rf,
                                                 qbuf, efpbuf);
    gemm2_mfma<<<dim3(256, 4), 256, 0, stream>>>(eg_bf, Wb2t, cs2, cst2, mg, rg,
                                                 kfull, vfull);
    pool_pass1<<<2048, 256, 0, stream>>>(kfull, vfull, kpart, vpart);
    pool_pass2<<<128, 256, 0, stream>>>(kpart, vpart, kp, vp);
    attn_dw<<<2048, 256, 0, stream>>>(qbuf, kp, vp, dwk, /*combined=*/kfull);
    gemm3_mfma<<<dim3(256, 2), 256, 0, stream>>>(/*combined=*/kfull, Wot, bo,
                                                 efpbuf, /*ea=*/vfull);
    gemm4_mfma<<<dim3(2, 256), 256, 0, stream>>>(Woc, /*ea=*/vfull, scv, shv, outp);
}

// Round 3
// 367.718 us; speedup vs baseline: 2.0616x; 1.0999x over previous
//
#include <hip/hip_runtime.h>
#include <math.h>

#define EPS 1e-5f

typedef __attribute__((ext_vector_type(8))) short bf16x8;
typedef __attribute__((ext_vector_type(4))) float f32x4;

__device__ __forceinline__ unsigned short f2bf(float f) {
    unsigned int u = __float_as_uint(f);
    u += 0x7fff + ((u >> 16) & 1);            // round-to-nearest-even
    return (unsigned short)(u >> 16);
}
__device__ __forceinline__ float bf2f(unsigned short h) {
    return __uint_as_float(((unsigned int)h) << 16);
}
__device__ __forceinline__ float lof(unsigned int u) {
    return __uint_as_float(u << 16);
}
__device__ __forceinline__ float hif(unsigned int u) {
    return __uint_as_float(u & 0xffff0000u);
}
__device__ __forceinline__ void async16(void* lds, const void* g) {
    __builtin_amdgcn_global_load_lds(
        (const __attribute__((address_space(1))) unsigned int*)g,
        (__attribute__((address_space(3))) unsigned int*)lds, 16, 0, 0);
}

// ---------------- prep: bf16 weight matrices in [N][K] (B-operand) layout ---
__global__ __launch_bounds__(256) void prep_weights_bf(
    const float* __restrict__ lnfg, const float* __restrict__ wq,
    const float* __restrict__ efpw,
    const float* __restrict__ lngg, const float* __restrict__ wk,
    const float* __restrict__ wv, const float* __restrict__ wo,
    const float* __restrict__ outcw,
    unsigned short* __restrict__ Wb1t, unsigned short* __restrict__ Wb2t,
    unsigned short* __restrict__ Wot, unsigned short* __restrict__ Woc)
{
    int idx = blockIdx.x * 256 + threadIdx.x;
    if (idx < 262144) {                       // Wb1t [n=512][k=512]: q | efp
        int n = idx >> 9, k = idx & 511;
        float v = (n < 256) ? lnfg[k] * wq[k * 256 + n]
                            : efpw[(size_t)(n - 256) * 512 + k];
        Wb1t[idx] = f2bf(v);
    } else if (idx < 393216) {                // Wb2t [n=512][k=256]: k | v
        int j = idx - 262144; int n = j >> 8, k = j & 255;
        float v = (n < 256) ? lngg[k] * wk[k * 256 + n]
                            : lngg[k] * wv[k * 256 + (n - 256)];
        Wb2t[j] = f2bf(v);
    } else if (idx < 458752) {                // Wot [256][256] = wo^T
        int j = idx - 393216; int n = j >> 8, k = j & 255;
        Wot[j] = f2bf(wo[k * 256 + n]);
    } else if (idx < 524288) {                // Woc [256][256] = outc_w (already [n][k])
        int j = idx - 458752;
        Woc[j] = f2bf(outcw[j]);
    }
}

// ---------------- fp32 column constants (LN folding) ------------------------
__global__ __launch_bounds__(256) void prep_cols(
    const float* __restrict__ lnfg, const float* __restrict__ lnfb,
    const float* __restrict__ wq, const float* __restrict__ bq,
    const float* __restrict__ efpb,
    const float* __restrict__ lngg, const float* __restrict__ lngb,
    const float* __restrict__ wk, const float* __restrict__ bk,
    const float* __restrict__ wv, const float* __restrict__ bv,
    const float* __restrict__ outcb, const float* __restrict__ bng,
    const float* __restrict__ bnb, const float* __restrict__ bnm,
    const float* __restrict__ bnv,
    float* __restrict__ cs1, float* __restrict__ cst1,
    float* __restrict__ cs2, float* __restrict__ cst2,
    float* __restrict__ scv, float* __restrict__ shv)
{
    int idx = blockIdx.x * 256 + threadIdx.x;
    if (idx < 256) {
        int n = idx; float cs = 0.f, ct = 0.f;
        for (int k = 0; k < 512; k++) {
            float w = wq[k * 256 + n];
            cs += lnfg[k] * w; ct += lnfb[k] * w;
        }
        cs1[n] = cs; cst1[n] = ct + bq[n];
    } else if (idx < 512) {
        cs1[idx] = 0.f; cst1[idx] = efpb[idx - 256];
    } else if (idx < 768) {
        int n = idx - 512; float cs = 0.f, ct = 0.f;
        for (int k = 0; k < 256; k++) {
            float w = wk[k * 256 + n];
            cs += lngg[k] * w; ct += lngb[k] * w;
        }
        cs2[n] = cs; cst2[n] = ct + bk[n];
    } else if (idx < 1024) {
        int n = idx - 768; float cs = 0.f, ct = 0.f;
        for (int k = 0; k < 256; k++) {
            float w = wv[k * 256 + n];
            cs += lngg[k] * w; ct += lngb[k] * w;
        }
        cs2[256 + n] = cs; cst2[256 + n] = ct + bv[n];
    } else if (idx < 1280) {
        int n = idx - 1024;
        float s = bng[n] * rsqrtf(bnv[n] + EPS);
        scv[n] = s;
        shv[n] = (outcb[n] - bnm[n]) * s + bnb[n];
    }
}

// ------- NCHW fp32 -> [M][C] bf16 transpose, fused LN partial stats ---------
__global__ __launch_bounds__(256) void transpose_cvt_stats(
    const float* __restrict__ src, unsigned short* __restrict__ dst,
    float* __restrict__ sumb, float* __restrict__ ssb, int C)
{
    __shared__ float tile[64][65];
    __shared__ float psum[4][64], pss[4][64];
    int b = blockIdx.z, c0 = blockIdx.y * 64, p0 = blockIdx.x * 64;
    const float* s = src + ((size_t)b * C + c0) * 4096 + p0;
    int t = threadIdx.x;
    int lane = t & 63, grp = t >> 6;
#pragma unroll
    for (int i = 0; i < 16; i++) {
        int c = i * 4 + grp;
        tile[c][lane] = s[(size_t)c * 4096 + lane];
    }
    __syncthreads();
    unsigned short* d = dst + ((size_t)(b * 4096 + p0)) * C + c0;
#pragma unroll
    for (int i = 0; i < 16; i++) {
        int p = i * 4 + grp;
        d[(size_t)p * C + lane] = f2bf(tile[lane][p]);
    }
    // per-position partial sums over this block's 64 channels
    float sm = 0.f, sq = 0.f;
#pragma unroll
    for (int j = 0; j < 16; j++) {
        float v = tile[grp * 16 + j][lane];     // position = lane
        sm += v; sq += v * v;
    }
    psum[grp][lane] = sm; pss[grp][lane] = sq;
    __syncthreads();
    if (t < 64) {
        float fs = psum[0][t] + psum[1][t] + psum[2][t] + psum[3][t];
        float fq = pss[0][t] + pss[1][t] + pss[2][t] + pss[3][t];
        atomicAdd(&sumb[b * 4096 + p0 + t], fs);
        atomicAdd(&ssb[b * 4096 + p0 + t], fq);
    }
}

__global__ __launch_bounds__(256) void ln_finalize(
    const float* __restrict__ sf, const float* __restrict__ ssf,
    const float* __restrict__ sg, const float* __restrict__ ssg,
    float* __restrict__ mf, float* __restrict__ rf,
    float* __restrict__ mg, float* __restrict__ rg)
{
    int gp = blockIdx.x * 256 + threadIdx.x;
    float m = sf[gp] * (1.f / 512.f);
    float v = ssf[gp] * (1.f / 512.f) - m * m;
    mf[gp] = m; rf[gp] = rsqrtf(v + EPS);
    m = sg[gp] * (1.f / 256.f);
    v = ssg[gp] * (1.f / 256.f) - m * m;
    mg[gp] = m; rg[gp] = rsqrtf(v + EPS);
}

// ---------------- MFMA GEMM core (m97-style) --------------------------------
template<int K>
__device__ __forceinline__ void mfma_core(
    const unsigned short* __restrict__ A, const unsigned short* __restrict__ Bt,
    int m0, int n0, unsigned short* As, unsigned short* Bs, f32x4 acc[4][4])
{
    const int tid = threadIdx.x;
    const int wave = tid >> 6, lane = tid & 63;
    const int wm = (wave & 1) * 64, wn = (wave >> 1) * 64;
#pragma unroll
    for (int i = 0; i < 4; i++)
#pragma unroll
        for (int j = 0; j < 4; j++) acc[i][j] = (f32x4){0.f, 0.f, 0.f, 0.f};

    const int srow = wave * 32 + (lane >> 3);
    const int sg = (lane & 7) ^ ((lane >> 3) & 7);
    const unsigned short* ga = A + (size_t)(m0 + srow) * K + sg * 8;
    const unsigned short* gb = Bt + (size_t)(n0 + srow) * K + sg * 8;

    for (int k0 = 0; k0 < K; k0 += 64) {
#pragma unroll
        for (int t = 0; t < 4; t++) {
            async16(As + (wave * 32 + t * 8) * 64, ga + (size_t)t * 8 * K + k0);
            async16(Bs + (wave * 32 + t * 8) * 64, gb + (size_t)t * 8 * K + k0);
        }
        __syncthreads();
#pragma unroll
        for (int ks = 0; ks < 2; ks++) {
            bf16x8 af[4], bfr[4];
            int kb = ks * 4 + (lane >> 4);
            int slot = (kb ^ (lane & 7)) * 8;
#pragma unroll
            for (int i = 0; i < 4; i++) {
                int m = wm + i * 16 + (lane & 15);
                af[i] = *(const bf16x8*)&As[m * 64 + slot];
                int n = wn + i * 16 + (lane & 15);
                bfr[i] = *(const bf16x8*)&Bs[n * 64 + slot];
            }
#pragma unroll
            for (int i = 0; i < 4; i++)
#pragma unroll
                for (int j = 0; j < 4; j++)
                    acc[i][j] = __builtin_amdgcn_mfma_f32_16x16x32_bf16(
                        af[i], bfr[j], acc[i][j], 0, 0, 0);
        }
        __syncthreads();
    }
}

// ---------------- GEMM1: ef_bf x Wb1t -> q (bf16, LN affine) | efp (fp32) ---
__global__ __launch_bounds__(256) void gemm1_mfma(
    const unsigned short* __restrict__ ef_bf, const unsigned short* __restrict__ Wb1t,
    const float* __restrict__ cs1, const float* __restrict__ cst1,
    const float* __restrict__ mf, const float* __restrict__ rf,
    unsigned short* __restrict__ qbuf, float* __restrict__ efpbuf)
{
    __shared__ unsigned short As[8192], Bs[8192];
    f32x4 acc[4][4];
    int m0 = blockIdx.x * 128, n0 = blockIdx.y * 128;
    mfma_core<512>(ef_bf, Wb1t, m0, n0, As, Bs, acc);
    int lane = threadIdx.x & 63, wave = threadIdx.x >> 6;
    int wm = (wave & 1) * 64, wn = (wave >> 1) * 64;
    bool isq = (n0 < 256);
#pragma unroll
    for (int i = 0; i < 4; i++) {
#pragma unroll
        for (int r = 0; r < 4; r++) {
            int gm = m0 + wm + i * 16 + ((lane >> 4) * 4) + r;
            float mean = mf[gm], rs = rf[gm];
#pragma unroll
            for (int j = 0; j < 4; j++) {
                int n = n0 + wn + j * 16 + (lane & 15);
                float v = acc[i][j][r];
                if (isq) {
                    float o = rs * (v - mean * cs1[n]) + cst1[n];
                    qbuf[(size_t)gm * 256 + n] = f2bf(o);
                } else {
                    efpbuf[(size_t)gm * 256 + (n - 256)] = v + cst1[n];
                }
            }
        }
    }
}

// ---------------- GEMM2: eg_bf x Wb2t -> kfull | vfull (bf16, LN affine) ----
__global__ __launch_bounds__(256) void gemm2_mfma(
    const unsigned short* __restrict__ eg_bf, const unsigned short* __restrict__ Wb2t,
    const float* __restrict__ cs2, const float* __restrict__ cst2,
    const float* __restrict__ mg, const float* __restrict__ rg,
    unsigned short* __restrict__ kfull, unsigned short* __restrict__ vfull)
{
    __shared__ unsigned short As[8192], Bs[8192];
    f32x4 acc[4][4];
    int m0 = blockIdx.x * 128, n0 = blockIdx.y * 128;
    mfma_core<256>(eg_bf, Wb2t, m0, n0, As, Bs, acc);
    int lane = threadIdx.x & 63, wave = threadIdx.x >> 6;
    int wm = (wave & 1) * 64, wn = (wave >> 1) * 64;
    unsigned short* dst = (n0 < 256) ? kfull : vfull;
    int nsub = (n0 < 256) ? 0 : 256;
#pragma unroll
    for (int i = 0; i < 4; i++) {
#pragma unroll
        for (int r = 0; r < 4; r++) {
            int gm = m0 + wm + i * 16 + ((lane >> 4) * 4) + r;
            float mean = mg[gm], rs = rg[gm];
#pragma unroll
            for (int j = 0; j < 4; j++) {
                int n = n0 + wn + j * 16 + (lane & 15);
                float o = rs * (acc[i][j][r] - mean * cs2[n]) + cst2[n];
                dst[(size_t)gm * 256 + (n - nsub)] = f2bf(o);
            }
        }
    }
}

// ---------------- GEMM3: combined x Wot, +bo, gate by efp -> ea (bf16) ------
__global__ __launch_bounds__(256) void gemm3_mfma(
    const unsigned short* __restrict__ comb, const unsigned short* __restrict__ Wot,
    const float* __restrict__ bo, const float* __restrict__ efp,
    unsigned short* __restrict__ ea)
{
    __shared__ unsigned short As[8192], Bs[8192];
    f32x4 acc[4][4];
    int m0 = blockIdx.x * 128, n0 = blockIdx.y * 128;
    mfma_core<256>(comb, Wot, m0, n0, As, Bs, acc);
    int lane = threadIdx.x & 63, wave = threadIdx.x >> 6;
    int wm = (wave & 1) * 64, wn = (wave >> 1) * 64;
#pragma unroll
    for (int i = 0; i < 4; i++) {
#pragma unroll
        for (int r = 0; r < 4; r++) {
            int gm = m0 + wm + i * 16 + ((lane >> 4) * 4) + r;
#pragma unroll
            for (int j = 0; j < 4; j++) {
                int n = n0 + wn + j * 16 + (lane & 15);
                float o = (acc[i][j][r] + bo[n]) * efp[(size_t)gm * 256 + n];
                ea[(size_t)gm * 256 + n] = f2bf(o);
            }
        }
    }
}

// ---------------- GEMM4 (transposed): Woc x ea^T -> out NCHW, BN+ReLU -------
__global__ __launch_bounds__(256) void gemm4_mfma(
    const unsigned short* __restrict__ Woc, const unsigned short* __restrict__ ea,
    const float* __restrict__ scv, const float* __restrict__ shv,
    float* __restrict__ outp)
{
    __shared__ unsigned short As[8192], Bs[8192];
    f32x4 acc[4][4];
    int m0 = blockIdx.x * 128, n0 = blockIdx.y * 128;
    mfma_core<256>(Woc, ea, m0, n0, As, Bs, acc);
    int lane = threadIdx.x & 63, wave = threadIdx.x >> 6;
    int wm = (wave & 1) * 64, wn = (wave >> 1) * 64;
#pragma unroll
    for (int i = 0; i < 4; i++) {
#pragma unroll
        for (int r = 0; r < 4; r++) {
            int co = m0 + wm + i * 16 + ((lane >> 4) * 4) + r;
            float s = scv[co], hh = shv[co];
#pragma unroll
            for (int j = 0; j < 4; j++) {
                int p = n0 + wn + j * 16 + (lane & 15);
                float o = fmaxf(fmaf(acc[i][j][r], s, hh), 0.f);
                outp[((size_t)(p >> 12)) * 1048576 + (size_t)co * 4096 + (p & 4095)] = o;
            }
        }
    }
}

// ---------------- 16x16 pooling (bf16 in, fp32 out) -------------------------
__global__ __launch_bounds__(256) void pool_pass1(
    const unsigned short* __restrict__ kfull, const unsigned short* __restrict__ vfull,
    float* __restrict__ kpart, float* __restrict__ vpart)
{
    int blk = blockIdx.x;
    int i = blk & 15, cell = (blk >> 4) & 15, b = blk >> 8;
    int hp = cell >> 2, wp = cell & 3;
    int o = threadIdx.x;
    int h = hp * 16 + i;
    float mx = -3.402823466e38f, sm = 0.f;
#pragma unroll 4
    for (int j = 0; j < 16; j++) {
        int p = h * 64 + wp * 16 + j;
        size_t base = ((size_t)(b * 4096 + p)) * 256 + o;
        mx = fmaxf(mx, bf2f(kfull[base]));
        sm += bf2f(vfull[base]);
    }
    kpart[(size_t)blk * 256 + o] = mx;
    vpart[(size_t)blk * 256 + o] = sm;
}

__global__ __launch_bounds__(256) void pool_pass2(
    const float* __restrict__ kpart, const float* __restrict__ vpart,
    float* __restrict__ kp, float* __restrict__ vp)
{
    int blk = blockIdx.x;
    int o = threadIdx.x;
    float mx = -3.402823466e38f, sm = 0.f;
#pragma unroll 4
    for (int i = 0; i < 16; i++) {
        mx = fmaxf(mx, kpart[((size_t)blk * 16 + i) * 256 + o]);
        sm += vpart[((size_t)blk * 16 + i) * 256 + o];
    }
    kp[(size_t)blk * 256 + o] = mx;
    vp[(size_t)blk * 256 + o] = sm * (1.f / 256.f);
}

// ------- attention (16 keys, MFMA scores) + depthwise 3x3 -> combined -------
// One block per (batch, image row h): 64 positions, 256 threads.
// Wave w owns positions w*16..w*16+15 end-to-end (scores -> softmax -> a_i+dw),
// so only ONE __syncthreads (after staging) is needed.
__global__ __launch_bounds__(256) void attn_dw(
    const unsigned short* __restrict__ qbuf, const float* __restrict__ kp,
    const float* __restrict__ vp, const float* __restrict__ dwk,
    unsigned short* __restrict__ combined)
{
    __shared__ unsigned short qs[64 * 264];   // row h, [pos][ch], +8 pad
    __shared__ unsigned short kps[16 * 264];  // pooled K (bf16 lossless: max of bf16)
    __shared__ float attns[64 * 16];
    int t = threadIdx.x;
    int lane = t & 63, wave = t >> 6;
    int b = blockIdx.x >> 6, h = blockIdx.x & 63;
    int row0 = b * 4096 + h * 64;

    // ---- stage q row h (32KB, coalesced uint4) ----
    const unsigned short* qrow = qbuf + (size_t)row0 * 256;
#pragma unroll
    for (int i = 0; i < 8; i++) {
        int idx = t + i * 256;                // 16B granule index
        int pos = idx >> 5, g = idx & 31;
        uint4 r = *(const uint4*)(qrow + idx * 8);
        *(uint4*)&qs[pos * 264 + g * 8] = r;
    }
    // ---- stage pooled K as bf16 ----
    {
        int cell = t >> 4, c4 = t & 15;       // 256 threads -> 16 cells x 16 float4
        float4 kv = *(const float4*)&kp[((size_t)(b * 16 + cell)) * 256 + c4 * 16];
        float4 kv2 = *(const float4*)&kp[((size_t)(b * 16 + cell)) * 256 + c4 * 16 + 4];
        float4 kv3 = *(const float4*)&kp[((size_t)(b * 16 + cell)) * 256 + c4 * 16 + 8];
        float4 kv4 = *(const float4*)&kp[((size_t)(b * 16 + cell)) * 256 + c4 * 16 + 12];
        uint4 pk;
        pk.x = (unsigned)f2bf(kv.x)  | ((unsigned)f2bf(kv.y)  << 16);
        pk.y = (unsigned)f2bf(kv.z)  | ((unsigned)f2bf(kv.w)  << 16);
        pk.z = (unsigned)f2bf(kv2.x) | ((unsigned)f2bf(kv2.y) << 16);
        pk.w = (unsigned)f2bf(kv2.z) | ((unsigned)f2bf(kv2.w) << 16);
        *(uint4*)&kps[cell * 264 + c4 * 16] = pk;
        pk.x = (unsigned)f2bf(kv3.x) | ((unsigned)f2bf(kv3.y) << 16);
        pk.y = (unsigned)f2bf(kv3.z) | ((unsigned)f2bf(kv3.w) << 16);
        pk.z = (unsigned)f2bf(kv4.x) | ((unsigned)f2bf(kv4.y) << 16);
        pk.w = (unsigned)f2bf(kv4.z) | ((unsigned)f2bf(kv4.w) << 16);
        *(uint4*)&kps[cell * 264 + c4 * 16 + 8] = pk;
    }
    // ---- per-lane register preloads (global, L1/L2-hot) ----
    int o4 = lane * 4;
    float4 vreg[16];
#pragma unroll
    for (int c = 0; c < 16; c++)
        vreg[c] = *(const float4*)&vp[((size_t)(b * 16 + c)) * 256 + o4];
    float4 kreg[9];
#pragma unroll
    for (int tap = 0; tap < 9; tap++) {
        kreg[tap].x = dwk[(o4 + 0) * 9 + tap];
        kreg[tap].y = dwk[(o4 + 1) * 9 + tap];
        kreg[tap].z = dwk[(o4 + 2) * 9 + tap];
        kreg[tap].w = dwk[(o4 + 3) * 9 + tap];
    }
    __syncthreads();

    // ---- scores via MFMA: wave w -> 16 positions x 16 cells, K=256 ----
    {
        int fr = lane & 15, kq = lane >> 4;
        f32x4 sacc = {0.f, 0.f, 0.f, 0.f};
#pragma unroll
        for (int ks = 0; ks < 8; ks++) {
            bf16x8 afr = *(const bf16x8*)&qs[(wave * 16 + fr) * 264 + ks * 32 + kq * 8];
            bf16x8 bfr = *(const bf16x8*)&kps[fr * 264 + ks * 32 + kq * 8];
            sacc = __builtin_amdgcn_mfma_f32_16x16x32_bf16(afr, bfr, sacc, 0, 0, 0);
        }
#pragma unroll
        for (int r = 0; r < 4; r++) {
            float s = sacc[r] * 0.0625f;       // HID^-0.5
            float mx = s;
#pragma unroll
            for (int off = 8; off >= 1; off >>= 1) mx = fmaxf(mx, __shfl_xor(mx, off));
            float e = __expf(s - mx);
            float sum = e;
#pragma unroll
            for (int off = 8; off >= 1; off >>= 1) sum += __shfl_xor(sum, off);
            int pos = wave * 16 + kq * 4 + r;
            attns[pos * 16 + fr] = e / sum;    // same-wave consumer below
        }
    }

    // ---- a_i (regs) + depthwise 3x3 -> combined ----
    for (int it = 0; it < 16; it++) {
        int pos = wave * 16 + it;
        float4 acc = {0.f, 0.f, 0.f, 0.f};
        const float* arow = &attns[pos * 16];
#pragma unroll
        for (int c = 0; c < 16; c++) {
            float a = arow[c];
            acc.x = fmaf(a, vreg[c].x, acc.x); acc.y = fmaf(a, vreg[c].y, acc.y);
            acc.z = fmaf(a, vreg[c].z, acc.z); acc.w = fmaf(a, vreg[c].w, acc.w);
        }
#pragma unroll
        for (int dy = 0; dy < 3; dy++) {
            int hh = h + dy - 1;
            if (hh < 0 || hh > 63) continue;               // block-uniform
#pragma unroll
            for (int dx = 0; dx < 3; dx++) {
                int xx = pos + dx - 1;
                if (xx < 0 || xx > 63) continue;           // wave-uniform
                float4 kk = kreg[dy * 3 + dx];
                uint2 qa;
                if (dy == 1) qa = *(const uint2*)&qs[xx * 264 + o4];
                else qa = *(const uint2*)(qbuf +
                         ((size_t)(b * 4096 + hh * 64 + xx)) * 256 + o4);
                acc.x = fmaf(lof(qa.x), kk.x, acc.x);
                acc.y = fmaf(hif(qa.x), kk.y, acc.y);
                acc.z = fmaf(lof(qa.y), kk.z, acc.z);
                acc.w = fmaf(hif(qa.y), kk.w, acc.w);
            }
        }
        uint2 pk;
        pk.x = (unsigned)f2bf(acc.x) | ((unsigned)f2bf(acc.y) << 16);
        pk.y = (unsigned)f2bf(acc.z) | ((unsigned)f2bf(acc.w) << 16);
        *(uint2*)(combined + (size_t)(row0 + pos) * 256 + o4) = pk;
    }
}

// ---------------------------------------------------------------------------
extern "C" void kernel_launch(void* const* d_in, const int* in_sizes, int n_in,
                              void* d_out, int out_size, void* d_ws, size_t ws_size,
                              hipStream_t stream)
{
    const float* e_f   = (const float*)d_in[0];
    const float* e_g   = (const float*)d_in[1];
    const float* lnfg  = (const float*)d_in[4];
    const float* lnfb  = (const float*)d_in[5];
    const float* lngg  = (const float*)d_in[6];
    const float* lngb  = (const float*)d_in[7];
    const float* wq    = (const float*)d_in[8];
    const float* bq    = (const float*)d_in[9];
    const float* wk    = (const float*)d_in[10];
    const float* bk    = (const float*)d_in[11];
    const float* wv    = (const float*)d_in[12];
    const float* bv    = (const float*)d_in[13];
    const float* wo    = (const float*)d_in[14];
    const float* bo    = (const float*)d_in[15];
    const float* dwk   = (const float*)d_in[16];
    const float* efpw  = (const float*)d_in[17];
    const float* efpb  = (const float*)d_in[18];
    const float* outcw = (const float*)d_in[19];
    const float* outcb = (const float*)d_in[20];
    const float* bng   = (const float*)d_in[21];
    const float* bnb   = (const float*)d_in[22];
    const float* bnm   = (const float*)d_in[23];
    const float* bnv   = (const float*)d_in[24];
    float* outp = (float*)d_out;

    char* base = (char*)d_ws;
    auto alloc = [&](size_t bytes) -> char* {
        char* r = base; base += (bytes + 255) & ~(size_t)255; return r;
    };
    // stats sum region (must be contiguous for single memset)
    float* sumf = (float*)alloc(4 * 32768 * 4);
    float* ssf  = sumf + 32768;
    float* sumg = sumf + 65536;
    float* ssg  = sumf + 98304;
    float* mf    = (float*)alloc(32768 * 4);
    float* rf    = (float*)alloc(32768 * 4);
    float* mg    = (float*)alloc(32768 * 4);
    float* rg    = (float*)alloc(32768 * 4);
    float* cs1   = (float*)alloc(512 * 4);
    float* cst1  = (float*)alloc(512 * 4);
    float* cs2   = (float*)alloc(512 * 4);
    float* cst2  = (float*)alloc(512 * 4);
    float* scv   = (float*)alloc(256 * 4);
    float* shv   = (float*)alloc(256 * 4);
    unsigned short* Wb1t = (unsigned short*)alloc(262144 * 2);
    unsigned short* Wb2t = (unsigned short*)alloc(131072 * 2);
    unsigned short* Wot  = (unsigned short*)alloc(65536 * 2);
    unsigned short* Woc  = (unsigned short*)alloc(65536 * 2);
    unsigned short* ef_bf = (unsigned short*)alloc((size_t)32768 * 512 * 2);
    unsigned short* eg_bf = (unsigned short*)alloc((size_t)32768 * 256 * 2);
    unsigned short* qbuf  = (unsigned short*)alloc((size_t)32768 * 256 * 2);
    float* efpbuf = (float*)alloc((size_t)32768 * 256 * 4);
    unsigned short* kfull = (unsigned short*)alloc((size_t)32768 * 256 * 2); // -> combined
    unsigned short* vfull = (unsigned short*)alloc((size_t)32768 * 256 * 2); // -> ea
    float* kpart = (float*)alloc((size_t)2048 * 256 * 4);
    float* vpart = (float*)alloc((size_t)2048 * 256 * 4);
    float* kp    = (float*)alloc(128 * 256 * 4);
    float* vp    = (float*)alloc(128 * 256 * 4);

    hipMemsetAsync(sumf, 0, 4 * 32768 * 4, stream);
    prep_weights_bf<<<2048, 256, 0, stream>>>(lnfg, wq, efpw, lngg, wk, wv, wo,
                                              outcw, Wb1t, Wb2t, Wot, Woc);
    prep_cols<<<5, 256, 0, stream>>>(lnfg, lnfb, wq, bq, efpb,
                                     lngg, lngb, wk, bk, wv, bv,
                                     outcb, bng, bnb, bnm, bnv,
                                     cs1, cst1, cs2, cst2, scv, shv);
    transpose_cvt_stats<<<dim3(64, 8, 8), 256, 0, stream>>>(e_f, ef_bf, sumf, ssf, 512);
    transpose_cvt_stats<<<dim3(64, 4, 8), 256, 0, stream>>>(e_g, eg_bf, sumg, ssg, 256);
    ln_finalize<<<128, 256, 0, stream>>>(sumf, ssf, sumg, ssg, mf, rf, mg, rg);
    gemm1_mfma<<<dim3(256, 4), 256, 0, stream>>>(ef_bf, Wb1t, cs1, cst1, mf, rf,
                                                 qbuf, efpbuf);
    gemm2_mfma<<<dim3(256, 4), 256, 0, stream>>>(eg_bf, Wb2t, cs2, cst2, mg, rg,
                                                 kfull, vfull);
    pool_pass1<<<2048, 256, 0, stream>>>(kfull, vfull, kpart, vpart);
    pool_pass2<<<128, 256, 0, stream>>>(kpart, vpart, kp, vp);
    attn_dw<<<512, 256, 0, stream>>>(qbuf, kp, vp, dwk, /*combined=*/kfull);
    gemm3_mfma<<<dim3(256, 2), 256, 0, stream>>>(/*combined=*/kfull, Wot, bo,
                                                 efpbuf, /*ea=*/vfull);
    gemm4_mfma<<<dim3(2, 256), 256, 0, stream>>>(Woc, /*ea=*/vfull, scv, shv, outp);
}

// Round 4
// 347.860 us; speedup vs baseline: 2.1793x; 1.0571x over previous
//
#include <hip/hip_runtime.h>
#include <math.h>

#define EPS 1e-5f

typedef __attribute__((ext_vector_type(8))) short bf16x8;
typedef __attribute__((ext_vector_type(4))) float f32x4;

__device__ __forceinline__ unsigned short f2bf(float f) {
    unsigned int u = __float_as_uint(f);
    u += 0x7fff + ((u >> 16) & 1);            // round-to-nearest-even
    return (unsigned short)(u >> 16);
}
__device__ __forceinline__ float bf2f(unsigned short h) {
    return __uint_as_float(((unsigned int)h) << 16);
}
__device__ __forceinline__ float lof(unsigned int u) {
    return __uint_as_float(u << 16);
}
__device__ __forceinline__ float hif(unsigned int u) {
    return __uint_as_float(u & 0xffff0000u);
}
__device__ __forceinline__ void async16(void* lds, const void* g) {
    __builtin_amdgcn_global_load_lds(
        (const __attribute__((address_space(1))) unsigned int*)g,
        (__attribute__((address_space(3))) unsigned int*)lds, 16, 0, 0);
}

// ---------------- prep: bf16 weights [N][K] + transposed dw taps ------------
__global__ __launch_bounds__(256) void prep_weights_bf(
    const float* __restrict__ lnfg, const float* __restrict__ wq,
    const float* __restrict__ efpw,
    const float* __restrict__ lngg, const float* __restrict__ wk,
    const float* __restrict__ wv, const float* __restrict__ wo,
    const float* __restrict__ outcw, const float* __restrict__ dwk,
    unsigned short* __restrict__ Wb1t, unsigned short* __restrict__ Wb2t,
    unsigned short* __restrict__ Wot, unsigned short* __restrict__ Woc,
    float* __restrict__ dwt)
{
    int idx = blockIdx.x * 256 + threadIdx.x;
    if (idx < 262144) {                       // Wb1t [n=512][k=512]: q | efp
        int n = idx >> 9, k = idx & 511;
        float v = (n < 256) ? lnfg[k] * wq[k * 256 + n]
                            : efpw[(size_t)(n - 256) * 512 + k];
        Wb1t[idx] = f2bf(v);
    } else if (idx < 393216) {                // Wb2t [n=512][k=256]: k | v
        int j = idx - 262144; int n = j >> 8, k = j & 255;
        float v = (n < 256) ? lngg[k] * wk[k * 256 + n]
                            : lngg[k] * wv[k * 256 + (n - 256)];
        Wb2t[j] = f2bf(v);
    } else if (idx < 458752) {                // Wot [256][256] = wo^T
        int j = idx - 393216; int n = j >> 8, k = j & 255;
        Wot[j] = f2bf(wo[k * 256 + n]);
    } else if (idx < 524288) {                // Woc [256][256] = outc_w
        int j = idx - 458752;
        Woc[j] = f2bf(outcw[j]);
    } else if (idx < 524288 + 2304) {         // dwt [tap][ch]
        int j = idx - 524288; int tap = j >> 8, ch = j & 255;
        dwt[j] = dwk[ch * 9 + tap];
    }
}

// ---------------- fp32 column constants (LN folding) ------------------------
__global__ __launch_bounds__(256) void prep_cols(
    const float* __restrict__ lnfg, const float* __restrict__ lnfb,
    const float* __restrict__ wq, const float* __restrict__ bq,
    const float* __restrict__ efpb,
    const float* __restrict__ lngg, const float* __restrict__ lngb,
    const float* __restrict__ wk, const float* __restrict__ bk,
    const float* __restrict__ wv, const float* __restrict__ bv,
    const float* __restrict__ outcb, const float* __restrict__ bng,
    const float* __restrict__ bnb, const float* __restrict__ bnm,
    const float* __restrict__ bnv,
    float* __restrict__ cs1, float* __restrict__ cst1,
    float* __restrict__ cs2, float* __restrict__ cst2,
    float* __restrict__ scv, float* __restrict__ shv)
{
    int idx = blockIdx.x * 256 + threadIdx.x;
    if (idx < 256) {
        int n = idx; float cs = 0.f, ct = 0.f;
        for (int k = 0; k < 512; k++) {
            float w = wq[k * 256 + n];
            cs += lnfg[k] * w; ct += lnfb[k] * w;
        }
        cs1[n] = cs; cst1[n] = ct + bq[n];
    } else if (idx < 512) {
        cs1[idx] = 0.f; cst1[idx] = efpb[idx - 256];
    } else if (idx < 768) {
        int n = idx - 512; float cs = 0.f, ct = 0.f;
        for (int k = 0; k < 256; k++) {
            float w = wk[k * 256 + n];
            cs += lngg[k] * w; ct += lngb[k] * w;
        }
        cs2[n] = cs; cst2[n] = ct + bk[n];
    } else if (idx < 1024) {
        int n = idx - 768; float cs = 0.f, ct = 0.f;
        for (int k = 0; k < 256; k++) {
            float w = wv[k * 256 + n];
            cs += lngg[k] * w; ct += lngb[k] * w;
        }
        cs2[256 + n] = cs; cst2[256 + n] = ct + bv[n];
    } else if (idx < 1280) {
        int n = idx - 1024;
        float s = bng[n] * rsqrtf(bnv[n] + EPS);
        scv[n] = s;
        shv[n] = (outcb[n] - bnm[n]) * s + bnb[n];
    }
}

// ------- NCHW fp32 -> [M][C] bf16 transpose, fused LN partial stats ---------
__global__ __launch_bounds__(256) void transpose_cvt_stats(
    const float* __restrict__ src, unsigned short* __restrict__ dst,
    float* __restrict__ sumb, float* __restrict__ ssb, int C)
{
    __shared__ float tile[64][65];
    __shared__ float psum[4][64], pss[4][64];
    int b = blockIdx.z, c0 = blockIdx.y * 64, p0 = blockIdx.x * 64;
    const float* s = src + ((size_t)b * C + c0) * 4096 + p0;
    int t = threadIdx.x;
    int lane = t & 63, grp = t >> 6;
#pragma unroll
    for (int i = 0; i < 16; i++) {
        int c = i * 4 + grp;
        tile[c][lane] = s[(size_t)c * 4096 + lane];
    }
    __syncthreads();
    unsigned short* d = dst + ((size_t)(b * 4096 + p0)) * C + c0;
#pragma unroll
    for (int i = 0; i < 16; i++) {
        int p = i * 4 + grp;
        d[(size_t)p * C + lane] = f2bf(tile[lane][p]);
    }
    float sm = 0.f, sq = 0.f;
#pragma unroll
    for (int j = 0; j < 16; j++) {
        float v = tile[grp * 16 + j][lane];
        sm += v; sq += v * v;
    }
    psum[grp][lane] = sm; pss[grp][lane] = sq;
    __syncthreads();
    if (t < 64) {
        float fs = psum[0][t] + psum[1][t] + psum[2][t] + psum[3][t];
        float fq = pss[0][t] + pss[1][t] + pss[2][t] + pss[3][t];
        atomicAdd(&sumb[b * 4096 + p0 + t], fs);
        atomicAdd(&ssb[b * 4096 + p0 + t], fq);
    }
}

__global__ __launch_bounds__(256) void ln_finalize(
    const float* __restrict__ sf, const float* __restrict__ ssf,
    const float* __restrict__ sg, const float* __restrict__ ssg,
    float* __restrict__ mf, float* __restrict__ rf,
    float* __restrict__ mg, float* __restrict__ rg)
{
    int gp = blockIdx.x * 256 + threadIdx.x;
    float m = sf[gp] * (1.f / 512.f);
    float v = ssf[gp] * (1.f / 512.f) - m * m;
    mf[gp] = m; rf[gp] = rsqrtf(v + EPS);
    m = sg[gp] * (1.f / 256.f);
    v = ssg[gp] * (1.f / 256.f) - m * m;
    mg[gp] = m; rg[gp] = rsqrtf(v + EPS);
}

// ---------------- MFMA GEMM core (m97-style) --------------------------------
template<int K>
__device__ __forceinline__ void mfma_core(
    const unsigned short* __restrict__ A, const unsigned short* __restrict__ Bt,
    int m0, int n0, unsigned short* As, unsigned short* Bs, f32x4 acc[4][4])
{
    const int tid = threadIdx.x;
    const int wave = tid >> 6, lane = tid & 63;
    const int wm = (wave & 1) * 64, wn = (wave >> 1) * 64;
#pragma unroll
    for (int i = 0; i < 4; i++)
#pragma unroll
        for (int j = 0; j < 4; j++) acc[i][j] = (f32x4){0.f, 0.f, 0.f, 0.f};

    const int srow = wave * 32 + (lane >> 3);
    const int sg = (lane & 7) ^ ((lane >> 3) & 7);
    const unsigned short* ga = A + (size_t)(m0 + srow) * K + sg * 8;
    const unsigned short* gb = Bt + (size_t)(n0 + srow) * K + sg * 8;

    for (int k0 = 0; k0 < K; k0 += 64) {
#pragma unroll
        for (int t = 0; t < 4; t++) {
            async16(As + (wave * 32 + t * 8) * 64, ga + (size_t)t * 8 * K + k0);
            async16(Bs + (wave * 32 + t * 8) * 64, gb + (size_t)t * 8 * K + k0);
        }
        __syncthreads();
#pragma unroll
        for (int ks = 0; ks < 2; ks++) {
            bf16x8 af[4], bfr[4];
            int kb = ks * 4 + (lane >> 4);
            int slot = (kb ^ (lane & 7)) * 8;
#pragma unroll
            for (int i = 0; i < 4; i++) {
                int m = wm + i * 16 + (lane & 15);
                af[i] = *(const bf16x8*)&As[m * 64 + slot];
                int n = wn + i * 16 + (lane & 15);
                bfr[i] = *(const bf16x8*)&Bs[n * 64 + slot];
            }
#pragma unroll
            for (int i = 0; i < 4; i++)
#pragma unroll
                for (int j = 0; j < 4; j++)
                    acc[i][j] = __builtin_amdgcn_mfma_f32_16x16x32_bf16(
                        af[i], bfr[j], acc[i][j], 0, 0, 0);
        }
        __syncthreads();
    }
}

// ---------------- GEMM1: ef_bf x Wb1t -> q (bf16, LN affine) | efp (bf16) ---
__global__ __launch_bounds__(256) void gemm1_mfma(
    const unsigned short* __restrict__ ef_bf, const unsigned short* __restrict__ Wb1t,
    const float* __restrict__ cs1, const float* __restrict__ cst1,
    const float* __restrict__ mf, const float* __restrict__ rf,
    unsigned short* __restrict__ qbuf, unsigned short* __restrict__ efpbuf)
{
    __shared__ unsigned short As[8192], Bs[8192];
    f32x4 acc[4][4];
    int m0 = blockIdx.x * 128, n0 = blockIdx.y * 128;
    mfma_core<512>(ef_bf, Wb1t, m0, n0, As, Bs, acc);
    int lane = threadIdx.x & 63, wave = threadIdx.x >> 6;
    int wm = (wave & 1) * 64, wn = (wave >> 1) * 64;
    bool isq = (n0 < 256);
#pragma unroll
    for (int i = 0; i < 4; i++) {
#pragma unroll
        for (int r = 0; r < 4; r++) {
            int gm = m0 + wm + i * 16 + ((lane >> 4) * 4) + r;
            float mean = mf[gm], rs = rf[gm];
#pragma unroll
            for (int j = 0; j < 4; j++) {
                int n = n0 + wn + j * 16 + (lane & 15);
                float v = acc[i][j][r];
                if (isq) {
                    float o = rs * (v - mean * cs1[n]) + cst1[n];
                    qbuf[(size_t)gm * 256 + n] = f2bf(o);
                } else {
                    efpbuf[(size_t)gm * 256 + (n - 256)] = f2bf(v + cst1[n]);
                }
            }
        }
    }
}

// ---------------- GEMM2: eg_bf x Wb2t -> kfull | vfull (bf16, LN affine) ----
__global__ __launch_bounds__(256) void gemm2_mfma(
    const unsigned short* __restrict__ eg_bf, const unsigned short* __restrict__ Wb2t,
    const float* __restrict__ cs2, const float* __restrict__ cst2,
    const float* __restrict__ mg, const float* __restrict__ rg,
    unsigned short* __restrict__ kfull, unsigned short* __restrict__ vfull)
{
    __shared__ unsigned short As[8192], Bs[8192];
    f32x4 acc[4][4];
    int m0 = blockIdx.x * 128, n0 = blockIdx.y * 128;
    mfma_core<256>(eg_bf, Wb2t, m0, n0, As, Bs, acc);
    int lane = threadIdx.x & 63, wave = threadIdx.x >> 6;
    int wm = (wave & 1) * 64, wn = (wave >> 1) * 64;
    unsigned short* dst = (n0 < 256) ? kfull : vfull;
    int nsub = (n0 < 256) ? 0 : 256;
#pragma unroll
    for (int i = 0; i < 4; i++) {
#pragma unroll
        for (int r = 0; r < 4; r++) {
            int gm = m0 + wm + i * 16 + ((lane >> 4) * 4) + r;
            float mean = mg[gm], rs = rg[gm];
#pragma unroll
            for (int j = 0; j < 4; j++) {
                int n = n0 + wn + j * 16 + (lane & 15);
                float o = rs * (acc[i][j][r] - mean * cs2[n]) + cst2[n];
                dst[(size_t)gm * 256 + (n - nsub)] = f2bf(o);
            }
        }
    }
}

// ---------------- GEMM3: combined x Wot, +bo, gate by efp(bf16) -> ea -------
__global__ __launch_bounds__(256) void gemm3_mfma(
    const unsigned short* __restrict__ comb, const unsigned short* __restrict__ Wot,
    const float* __restrict__ bo, const unsigned short* __restrict__ efp,
    unsigned short* __restrict__ ea)
{
    __shared__ unsigned short As[8192], Bs[8192];
    f32x4 acc[4][4];
    int m0 = blockIdx.x * 128, n0 = blockIdx.y * 128;
    mfma_core<256>(comb, Wot, m0, n0, As, Bs, acc);
    int lane = threadIdx.x & 63, wave = threadIdx.x >> 6;
    int wm = (wave & 1) * 64, wn = (wave >> 1) * 64;
#pragma unroll
    for (int i = 0; i < 4; i++) {
#pragma unroll
        for (int r = 0; r < 4; r++) {
            int gm = m0 + wm + i * 16 + ((lane >> 4) * 4) + r;
#pragma unroll
            for (int j = 0; j < 4; j++) {
                int n = n0 + wn + j * 16 + (lane & 15);
                float o = (acc[i][j][r] + bo[n]) * bf2f(efp[(size_t)gm * 256 + n]);
                ea[(size_t)gm * 256 + n] = f2bf(o);
            }
        }
    }
}

// ---------------- GEMM4 (transposed): Woc x ea^T -> out NCHW, BN+ReLU -------
__global__ __launch_bounds__(256) void gemm4_mfma(
    const unsigned short* __restrict__ Woc, const unsigned short* __restrict__ ea,
    const float* __restrict__ scv, const float* __restrict__ shv,
    float* __restrict__ outp)
{
    __shared__ unsigned short As[8192], Bs[8192];
    f32x4 acc[4][4];
    int m0 = blockIdx.x * 128, n0 = blockIdx.y * 128;
    mfma_core<256>(Woc, ea, m0, n0, As, Bs, acc);
    int lane = threadIdx.x & 63, wave = threadIdx.x >> 6;
    int wm = (wave & 1) * 64, wn = (wave >> 1) * 64;
#pragma unroll
    for (int i = 0; i < 4; i++) {
#pragma unroll
        for (int r = 0; r < 4; r++) {
            int co = m0 + wm + i * 16 + ((lane >> 4) * 4) + r;
            float s = scv[co], hh = shv[co];
#pragma unroll
            for (int j = 0; j < 4; j++) {
                int p = n0 + wn + j * 16 + (lane & 15);
                float o = fmaxf(fmaf(acc[i][j][r], s, hh), 0.f);
                outp[((size_t)(p >> 12)) * 1048576 + (size_t)co * 4096 + (p & 4095)] = o;
            }
        }
    }
}

// ---------------- fused 16x16 pooling: one block per (b, cell) --------------
__global__ __launch_bounds__(256) void pool_fused(
    const unsigned short* __restrict__ kfull, const unsigned short* __restrict__ vfull,
    unsigned short* __restrict__ kpb, float* __restrict__ vp)
{
    __shared__ float kmax_s[8 * 256], vsum_s[8 * 256];
    int id = blockIdx.x;                 // 128 = 8 b x 16 cells
    int b = id >> 4, cell = id & 15;
    int hp = cell >> 2, wp = cell & 3;
    int t = threadIdx.x;
    int g8 = t & 31, rr = t >> 5;        // 16B channel-granule, row-pair
    float kmx[8], vsm[8];
#pragma unroll
    for (int j = 0; j < 8; j++) { kmx[j] = -3.402823466e38f; vsm[j] = 0.f; }
#pragma unroll
    for (int rsub = 0; rsub < 2; rsub++) {
        int r = rr * 2 + rsub;
        int prow = (hp * 16 + r) * 64 + wp * 16;
        for (int cl = 0; cl < 16; cl++) {
            size_t basei = ((size_t)(b * 4096 + prow + cl)) * 256 + g8 * 8;
            uint4 kv = *(const uint4*)(kfull + basei);
            uint4 vv = *(const uint4*)(vfull + basei);
            kmx[0] = fmaxf(kmx[0], lof(kv.x)); kmx[1] = fmaxf(kmx[1], hif(kv.x));
            kmx[2] = fmaxf(kmx[2], lof(kv.y)); kmx[3] = fmaxf(kmx[3], hif(kv.y));
            kmx[4] = fmaxf(kmx[4], lof(kv.z)); kmx[5] = fmaxf(kmx[5], hif(kv.z));
            kmx[6] = fmaxf(kmx[6], lof(kv.w)); kmx[7] = fmaxf(kmx[7], hif(kv.w));
            vsm[0] += lof(vv.x); vsm[1] += hif(vv.x);
            vsm[2] += lof(vv.y); vsm[3] += hif(vv.y);
            vsm[4] += lof(vv.z); vsm[5] += hif(vv.z);
            vsm[6] += lof(vv.w); vsm[7] += hif(vv.w);
        }
    }
#pragma unroll
    for (int j = 0; j < 8; j++) {
        kmax_s[rr * 256 + g8 * 8 + j] = kmx[j];
        vsum_s[rr * 256 + g8 * 8 + j] = vsm[j];
    }
    __syncthreads();
    int o = t;
    float m = kmax_s[o], s = vsum_s[o];
#pragma unroll
    for (int r2 = 1; r2 < 8; r2++) {
        m = fmaxf(m, kmax_s[r2 * 256 + o]);
        s += vsum_s[r2 * 256 + o];
    }
    kpb[(size_t)(b * 16 + cell) * 256 + o] = f2bf(m);   // lossless: max of bf16
    vp [(size_t)(b * 16 + cell) * 256 + o] = s * (1.f / 256.f);
}

// ---------------- attention weights: MFMA scores + softmax, no LDS ----------
// Wave handles 16 positions x 16 cells, K=256. Fragments loaded from global.
__global__ __launch_bounds__(256) void attn_w(
    const unsigned short* __restrict__ qbuf, const unsigned short* __restrict__ kpb,
    float* __restrict__ attns)
{
    int wave = threadIdx.x >> 6, lane = threadIdx.x & 63;
    int id = blockIdx.x;                 // 512
    int b = id & 7, seg = id >> 3;       // XCD-local batch
    int m0 = b * 4096 + seg * 64 + wave * 16;
    int fr = lane & 15, quad = lane >> 4;
    const unsigned short* qrow = qbuf + (size_t)(m0 + fr) * 256 + quad * 8;
    const unsigned short* krow = kpb + (size_t)(b * 16 + fr) * 256 + quad * 8;
    f32x4 sacc = {0.f, 0.f, 0.f, 0.f};
#pragma unroll
    for (int ks = 0; ks < 8; ks++) {
        bf16x8 af = *(const bf16x8*)(qrow + ks * 32);
        bf16x8 bf_ = *(const bf16x8*)(krow + ks * 32);
        sacc = __builtin_amdgcn_mfma_f32_16x16x32_bf16(af, bf_, sacc, 0, 0, 0);
    }
#pragma unroll
    for (int r = 0; r < 4; r++) {
        float s = sacc[r] * 0.0625f;     // HID^-0.5
        float mx = s;
#pragma unroll
        for (int off = 8; off >= 1; off >>= 1) mx = fmaxf(mx, __shfl_xor(mx, off));
        float e = __expf(s - mx);
        float sum = e;
#pragma unroll
        for (int off = 8; off >= 1; off >>= 1) sum += __shfl_xor(sum, off);
        attns[(size_t)(m0 + quad * 4 + r) * 16 + fr] = e / sum;
    }
}

// ---------------- combined = attn@vp + dw3x3(q), no LDS ---------------------
// Wave = 4 consecutive positions (same image row), lane = 4 channels.
// b = blockIdx.x & 7 -> batch pinned per XCD (q row reuse in L2).
__global__ __launch_bounds__(256) void combined_dw(
    const unsigned short* __restrict__ qbuf, const float* __restrict__ attns,
    const float* __restrict__ vp, const float* __restrict__ dwt,
    unsigned short* __restrict__ combined)
{
    int wave = threadIdx.x >> 6, lane = threadIdx.x & 63;
    int id = blockIdx.x;                 // 2048
    int b = id & 7, seg = id >> 3;       // seg 0..255
    int pidx = seg * 16 + wave * 4;      // first of 4 positions (same row)
    int h = pidx >> 6, w0 = pidx & 63;
    int o4 = lane * 4;

    float4 kreg[9];
#pragma unroll
    for (int tap = 0; tap < 9; tap++)
        kreg[tap] = *(const float4*)&dwt[tap * 256 + o4];

    float4 acc[4];
#pragma unroll
    for (int i = 0; i < 4; i++) acc[i] = (float4){0.f, 0.f, 0.f, 0.f};

    // a_i: vp L1-resident (16 KB/batch)
    const float* arow = attns + (size_t)(b * 4096 + pidx) * 16;
#pragma unroll
    for (int c = 0; c < 16; c++) {
        float4 v = *(const float4*)&vp[(size_t)(b * 16 + c) * 256 + o4];
#pragma unroll
        for (int i = 0; i < 4; i++) {
            float a = arow[i * 16 + c];
            acc[i].x = fmaf(a, v.x, acc[i].x); acc[i].y = fmaf(a, v.y, acc[i].y);
            acc[i].z = fmaf(a, v.z, acc[i].z); acc[i].w = fmaf(a, v.w, acc[i].w);
        }
    }
    // depthwise 3x3: 6-column strip x 3 rows, taps shared across the 4 outputs
#pragma unroll
    for (int dy = 0; dy < 3; dy++) {
        int hh = h + dy - 1;
        if (hh < 0 || hh > 63) continue;           // wave-uniform
        const unsigned short* qr = qbuf + ((size_t)(b * 4096 + hh * 64)) * 256;
        float4 ft[6];
#pragma unroll
        for (int c = 0; c < 6; c++) {
            int xx = w0 - 1 + c;
            if (xx < 0 || xx > 63) {
                ft[c] = (float4){0.f, 0.f, 0.f, 0.f};
            } else {
                uint2 qa = *(const uint2*)(qr + (size_t)xx * 256 + o4);
                ft[c] = (float4){lof(qa.x), hif(qa.x), lof(qa.y), hif(qa.y)};
            }
        }
#pragma unroll
        for (int dx = 0; dx < 3; dx++) {
            float4 kk = kreg[dy * 3 + dx];
#pragma unroll
            for (int i = 0; i < 4; i++) {
                float4 qv = ft[i + dx];
                acc[i].x = fmaf(qv.x, kk.x, acc[i].x);
                acc[i].y = fmaf(qv.y, kk.y, acc[i].y);
                acc[i].z = fmaf(qv.z, kk.z, acc[i].z);
                acc[i].w = fmaf(qv.w, kk.w, acc[i].w);
            }
        }
    }
#pragma unroll
    for (int i = 0; i < 4; i++) {
        uint2 pk;
        pk.x = (unsigned)f2bf(acc[i].x) | ((unsigned)f2bf(acc[i].y) << 16);
        pk.y = (unsigned)f2bf(acc[i].z) | ((unsigned)f2bf(acc[i].w) << 16);
        *(uint2*)(combined + ((size_t)(b * 4096 + pidx + i)) * 256 + o4) = pk;
    }
}

// ---------------------------------------------------------------------------
extern "C" void kernel_launch(void* const* d_in, const int* in_sizes, int n_in,
                              void* d_out, int out_size, void* d_ws, size_t ws_size,
                              hipStream_t stream)
{
    const float* e_f   = (const float*)d_in[0];
    const float* e_g   = (const float*)d_in[1];
    const float* lnfg  = (const float*)d_in[4];
    const float* lnfb  = (const float*)d_in[5];
    const float* lngg  = (const float*)d_in[6];
    const float* lngb  = (const float*)d_in[7];
    const float* wq    = (const float*)d_in[8];
    const float* bq    = (const float*)d_in[9];
    const float* wk    = (const float*)d_in[10];
    const float* bk    = (const float*)d_in[11];
    const float* wv    = (const float*)d_in[12];
    const float* bv    = (const float*)d_in[13];
    const float* wo    = (const float*)d_in[14];
    const float* bo    = (const float*)d_in[15];
    const float* dwk   = (const float*)d_in[16];
    const float* efpw  = (const float*)d_in[17];
    const float* efpb  = (const float*)d_in[18];
    const float* outcw = (const float*)d_in[19];
    const float* outcb = (const float*)d_in[20];
    const float* bng   = (const float*)d_in[21];
    const float* bnb   = (const float*)d_in[22];
    const float* bnm   = (const float*)d_in[23];
    const float* bnv   = (const float*)d_in[24];
    float* outp = (float*)d_out;

    char* base = (char*)d_ws;
    auto alloc = [&](size_t bytes) -> char* {
        char* r = base; base += (bytes + 255) & ~(size_t)255; return r;
    };
    float* sumf = (float*)alloc(4 * 32768 * 4);
    float* ssf  = sumf + 32768;
    float* sumg = sumf + 65536;
    float* ssg  = sumf + 98304;
    float* mf    = (float*)alloc(32768 * 4);
    float* rf    = (float*)alloc(32768 * 4);
    float* mg    = (float*)alloc(32768 * 4);
    float* rg    = (float*)alloc(32768 * 4);
    float* cs1   = (float*)alloc(512 * 4);
    float* cst1  = (float*)alloc(512 * 4);
    float* cs2   = (float*)alloc(512 * 4);
    float* cst2  = (float*)alloc(512 * 4);
    float* scv   = (float*)alloc(256 * 4);
    float* shv   = (float*)alloc(256 * 4);
    float* dwt   = (float*)alloc(9 * 256 * 4);
    unsigned short* Wb1t = (unsigned short*)alloc(262144 * 2);
    unsigned short* Wb2t = (unsigned short*)alloc(131072 * 2);
    unsigned short* Wot  = (unsigned short*)alloc(65536 * 2);
    unsigned short* Woc  = (unsigned short*)alloc(65536 * 2);
    unsigned short* ef_bf = (unsigned short*)alloc((size_t)32768 * 512 * 2);
    unsigned short* eg_bf = (unsigned short*)alloc((size_t)32768 * 256 * 2);
    unsigned short* qbuf  = (unsigned short*)alloc((size_t)32768 * 256 * 2);
    unsigned short* efpbuf = (unsigned short*)alloc((size_t)32768 * 256 * 2);
    unsigned short* kfull = (unsigned short*)alloc((size_t)32768 * 256 * 2); // -> combined
    unsigned short* vfull = (unsigned short*)alloc((size_t)32768 * 256 * 2); // -> ea
    unsigned short* kpb  = (unsigned short*)alloc(128 * 256 * 2);
    float* vp    = (float*)alloc(128 * 256 * 4);
    float* attns = (float*)alloc((size_t)32768 * 16 * 4);

    hipMemsetAsync(sumf, 0, 4 * 32768 * 4, stream);
    prep_weights_bf<<<2057, 256, 0, stream>>>(lnfg, wq, efpw, lngg, wk, wv, wo,
                                              outcw, dwk, Wb1t, Wb2t, Wot, Woc, dwt);
    prep_cols<<<5, 256, 0, stream>>>(lnfg, lnfb, wq, bq, efpb,
                                     lngg, lngb, wk, bk, wv, bv,
                                     outcb, bng, bnb, bnm, bnv,
                                     cs1, cst1, cs2, cst2, scv, shv);
    transpose_cvt_stats<<<dim3(64, 8, 8), 256, 0, stream>>>(e_f, ef_bf, sumf, ssf, 512);
    transpose_cvt_stats<<<dim3(64, 4, 8), 256, 0, stream>>>(e_g, eg_bf, sumg, ssg, 256);
    ln_finalize<<<128, 256, 0, stream>>>(sumf, ssf, sumg, ssg, mf, rf, mg, rg);
    gemm1_mfma<<<dim3(256, 4), 256, 0, stream>>>(ef_bf, Wb1t, cs1, cst1, mf, rf,
                                                 qbuf, efpbuf);
    gemm2_mfma<<<dim3(256, 4), 256, 0, stream>>>(eg_bf, Wb2t, cs2, cst2, mg, rg,
                                                 kfull, vfull);
    pool_fused<<<128, 256, 0, stream>>>(kfull, vfull, kpb, vp);
    attn_w<<<512, 256, 0, stream>>>(qbuf, kpb, attns);
    combined_dw<<<2048, 256, 0, stream>>>(qbuf, attns, vp, dwt, /*combined=*/kfull);
    gemm3_mfma<<<dim3(256, 2), 256, 0, stream>>>(/*combined=*/kfull, Wot, bo,
                                                 efpbuf, /*ea=*/vfull);
    gemm4_mfma<<<dim3(2, 256), 256, 0, stream>>>(Woc, /*ea=*/vfull, scv, shv, outp);
}

// Round 5
// 339.972 us; speedup vs baseline: 2.2299x; 1.0232x over previous
//
#include <hip/hip_runtime.h>
#include <math.h>

#define EPS 1e-5f

typedef __attribute__((ext_vector_type(8))) short bf16x8;
typedef __attribute__((ext_vector_type(4))) float f32x4;

__device__ __forceinline__ unsigned short f2bf(float f) {
    unsigned int u = __float_as_uint(f);
    u += 0x7fff + ((u >> 16) & 1);            // round-to-nearest-even
    return (unsigned short)(u >> 16);
}
__device__ __forceinline__ float bf2f(unsigned short h) {
    return __uint_as_float(((unsigned int)h) << 16);
}
__device__ __forceinline__ float lof(unsigned int u) {
    return __uint_as_float(u << 16);
}
__device__ __forceinline__ float hif(unsigned int u) {
    return __uint_as_float(u & 0xffff0000u);
}
__device__ __forceinline__ void async16(void* lds, const void* g) {
    __builtin_amdgcn_global_load_lds(
        (const __attribute__((address_space(1))) unsigned int*)g,
        (__attribute__((address_space(3))) unsigned int*)lds, 16, 0, 0);
}

// ---------------- prep: everything weight-side in ONE kernel ----------------
__global__ __launch_bounds__(256) void prep_all(
    const float* __restrict__ lnfg, const float* __restrict__ lnfb,
    const float* __restrict__ wq, const float* __restrict__ bq,
    const float* __restrict__ efpw, const float* __restrict__ efpb,
    const float* __restrict__ lngg, const float* __restrict__ lngb,
    const float* __restrict__ wk, const float* __restrict__ bk,
    const float* __restrict__ wv, const float* __restrict__ bv,
    const float* __restrict__ wo, const float* __restrict__ outcw,
    const float* __restrict__ outcb, const float* __restrict__ bng,
    const float* __restrict__ bnb, const float* __restrict__ bnm,
    const float* __restrict__ bnv, const float* __restrict__ dwk,
    unsigned short* __restrict__ Wb1t, unsigned short* __restrict__ Wb2t,
    unsigned short* __restrict__ Wot, unsigned short* __restrict__ Woc,
    float* __restrict__ dwt,
    float* __restrict__ cs1, float* __restrict__ cst1,
    float* __restrict__ cs2, float* __restrict__ cst2,
    float* __restrict__ scv, float* __restrict__ shv)
{
    int idx = blockIdx.x * 256 + threadIdx.x;
    if (idx < 262144) {                       // Wb1t [n=512][k=512]: q | efp
        int n = idx >> 9, k = idx & 511;
        float v = (n < 256) ? lnfg[k] * wq[k * 256 + n]
                            : efpw[(size_t)(n - 256) * 512 + k];
        Wb1t[idx] = f2bf(v);
    } else if (idx < 327680) {                // Wb2t [n=256][k=256]: k only
        int j = idx - 262144; int n = j >> 8, k = j & 255;
        Wb2t[j] = f2bf(lngg[k] * wk[k * 256 + n]);
    } else if (idx < 393216) {                // Wot [256][256] = wo^T
        int j = idx - 327680; int n = j >> 8, k = j & 255;
        Wot[j] = f2bf(wo[k * 256 + n]);
    } else if (idx < 458752) {                // Woc [256][256] = outc_w
        int j = idx - 393216;
        Woc[j] = f2bf(outcw[j]);
    } else if (idx < 461056) {                // dwt [tap][ch]
        int j = idx - 458752; int tap = j >> 8, ch = j & 255;
        dwt[j] = dwk[ch * 9 + tap];
    } else if (idx < 462336) {                // column constants
        int j = idx - 461056;
        if (j < 256) {
            int n = j; float cs = 0.f, ct = 0.f;
            for (int k = 0; k < 512; k++) {
                float w = wq[k * 256 + n];
                cs += lnfg[k] * w; ct += lnfb[k] * w;
            }
            cs1[n] = cs; cst1[n] = ct + bq[n];
        } else if (j < 512) {
            cs1[j] = 0.f; cst1[j] = efpb[j - 256];
        } else if (j < 768) {
            int n = j - 512; float cs = 0.f, ct = 0.f;
            for (int k = 0; k < 256; k++) {
                float w = wk[k * 256 + n];
                cs += lngg[k] * w; ct += lngb[k] * w;
            }
            cs2[n] = cs; cst2[n] = ct + bk[n];
        } else if (j < 1024) {
            int n = j - 768; float cs = 0.f, ct = 0.f;
            for (int k = 0; k < 256; k++) {
                float w = wv[k * 256 + n];
                cs += lngg[k] * w; ct += lngb[k] * w;
            }
            cs2[256 + n] = cs; cst2[256 + n] = ct + bv[n];
        } else {
            int n = j - 1024;
            float s = bng[n] * rsqrtf(bnv[n] + EPS);
            scv[n] = s;
            shv[n] = (outcb[n] - bnm[n]) * s + bnb[n];
        }
    }
}

// ------- NCHW fp32 -> [M][C] bf16 transpose, partial LN stats (no atomics) --
__global__ __launch_bounds__(256) void transpose_fg(
    const float* __restrict__ ef, const float* __restrict__ eg,
    unsigned short* __restrict__ ef_bf, unsigned short* __restrict__ eg_bf,
    float* __restrict__ pf, float* __restrict__ pfq,
    float* __restrict__ pg, float* __restrict__ pgq)
{
    __shared__ float tile[64][65];
    __shared__ float psum[4][64], pss[4][64];
    int id = blockIdx.x;
    const float* src; unsigned short* dst; float* ps; float* pq;
    int C, cblk, b, p0;
    if (id < 4096) {
        src = ef; dst = ef_bf; ps = pf; pq = pfq; C = 512;
        p0 = (id & 63) * 64; cblk = (id >> 6) & 7; b = id >> 9;
    } else {
        id -= 4096;
        src = eg; dst = eg_bf; ps = pg; pq = pgq; C = 256;
        p0 = (id & 63) * 64; cblk = (id >> 6) & 3; b = id >> 8;
    }
    int c0 = cblk * 64;
    const float* s = src + ((size_t)b * C + c0) * 4096 + p0;
    int t = threadIdx.x;
    int lane = t & 63, grp = t >> 6;
#pragma unroll
    for (int i = 0; i < 16; i++) {
        int c = i * 4 + grp;
        tile[c][lane] = s[(size_t)c * 4096 + lane];
    }
    __syncthreads();
    unsigned short* d = dst + ((size_t)(b * 4096 + p0)) * C + c0;
#pragma unroll
    for (int i = 0; i < 16; i++) {
        int p = i * 4 + grp;
        d[(size_t)p * C + lane] = f2bf(tile[lane][p]);
    }
    float sm = 0.f, sq = 0.f;
#pragma unroll
    for (int j = 0; j < 16; j++) {
        float v = tile[grp * 16 + j][lane];
        sm += v; sq += v * v;
    }
    psum[grp][lane] = sm; pss[grp][lane] = sq;
    __syncthreads();
    if (t < 64) {
        float fs = psum[0][t] + psum[1][t] + psum[2][t] + psum[3][t];
        float fq = pss[0][t] + pss[1][t] + pss[2][t] + pss[3][t];
        ps[cblk * 32768 + b * 4096 + p0 + t] = fs;
        pq[cblk * 32768 + b * 4096 + p0 + t] = fq;
    }
}

__global__ __launch_bounds__(256) void ln_finalize(
    const float* __restrict__ pf, const float* __restrict__ pfq,
    const float* __restrict__ pg, const float* __restrict__ pgq,
    float* __restrict__ mf, float* __restrict__ rf,
    float* __restrict__ mg, float* __restrict__ rg)
{
    int gp = blockIdx.x * 256 + threadIdx.x;
    float s = 0.f, q = 0.f;
#pragma unroll
    for (int i = 0; i < 8; i++) { s += pf[i * 32768 + gp]; q += pfq[i * 32768 + gp]; }
    float m = s * (1.f / 512.f);
    float v = q * (1.f / 512.f) - m * m;
    mf[gp] = m; rf[gp] = rsqrtf(v + EPS);
    s = 0.f; q = 0.f;
#pragma unroll
    for (int i = 0; i < 4; i++) { s += pg[i * 32768 + gp]; q += pgq[i * 32768 + gp]; }
    m = s * (1.f / 256.f);
    v = q * (1.f / 256.f) - m * m;
    mg[gp] = m; rg[gp] = rsqrtf(v + EPS);
}

// ---------------- MFMA GEMM core (m97-style) --------------------------------
template<int K>
__device__ __forceinline__ void mfma_core(
    const unsigned short* __restrict__ A, const unsigned short* __restrict__ Bt,
    int m0, int n0, unsigned short* As, unsigned short* Bs, f32x4 acc[4][4])
{
    const int tid = threadIdx.x;
    const int wave = tid >> 6, lane = tid & 63;
    const int wm = (wave & 1) * 64, wn = (wave >> 1) * 64;
#pragma unroll
    for (int i = 0; i < 4; i++)
#pragma unroll
        for (int j = 0; j < 4; j++) acc[i][j] = (f32x4){0.f, 0.f, 0.f, 0.f};

    const int srow = wave * 32 + (lane >> 3);
    const int sg = (lane & 7) ^ ((lane >> 3) & 7);
    const unsigned short* ga = A + (size_t)(m0 + srow) * K + sg * 8;
    const unsigned short* gb = Bt + (size_t)(n0 + srow) * K + sg * 8;

    for (int k0 = 0; k0 < K; k0 += 64) {
#pragma unroll
        for (int t = 0; t < 4; t++) {
            async16(As + (wave * 32 + t * 8) * 64, ga + (size_t)t * 8 * K + k0);
            async16(Bs + (wave * 32 + t * 8) * 64, gb + (size_t)t * 8 * K + k0);
        }
        __syncthreads();
#pragma unroll
        for (int ks = 0; ks < 2; ks++) {
            bf16x8 af[4], bfr[4];
            int kb = ks * 4 + (lane >> 4);
            int slot = (kb ^ (lane & 7)) * 8;
#pragma unroll
            for (int i = 0; i < 4; i++) {
                int m = wm + i * 16 + (lane & 15);
                af[i] = *(const bf16x8*)&As[m * 64 + slot];
                int n = wn + i * 16 + (lane & 15);
                bfr[i] = *(const bf16x8*)&Bs[n * 64 + slot];
            }
#pragma unroll
            for (int i = 0; i < 4; i++)
#pragma unroll
                for (int j = 0; j < 4; j++)
                    acc[i][j] = __builtin_amdgcn_mfma_f32_16x16x32_bf16(
                        af[i], bfr[j], acc[i][j], 0, 0, 0);
        }
        __syncthreads();
    }
}

// ---------------- GEMM1: ef_bf x Wb1t -> q (bf16, LN affine) | efp (bf16) ---
__global__ __launch_bounds__(256) void gemm1_mfma(
    const unsigned short* __restrict__ ef_bf, const unsigned short* __restrict__ Wb1t,
    const float* __restrict__ cs1, const float* __restrict__ cst1,
    const float* __restrict__ mf, const float* __restrict__ rf,
    unsigned short* __restrict__ qbuf, unsigned short* __restrict__ efpbuf)
{
    __shared__ unsigned short As[8192], Bs[8192];
    f32x4 acc[4][4];
    int m0 = blockIdx.x * 128, n0 = blockIdx.y * 128;
    mfma_core<512>(ef_bf, Wb1t, m0, n0, As, Bs, acc);
    int lane = threadIdx.x & 63, wave = threadIdx.x >> 6;
    int wm = (wave & 1) * 64, wn = (wave >> 1) * 64;
    bool isq = (n0 < 256);
#pragma unroll
    for (int i = 0; i < 4; i++) {
#pragma unroll
        for (int r = 0; r < 4; r++) {
            int gm = m0 + wm + i * 16 + ((lane >> 4) * 4) + r;
            float mean = mf[gm], rs = rf[gm];
#pragma unroll
            for (int j = 0; j < 4; j++) {
                int n = n0 + wn + j * 16 + (lane & 15);
                float v = acc[i][j][r];
                if (isq) {
                    float o = rs * (v - mean * cs1[n]) + cst1[n];
                    qbuf[(size_t)gm * 256 + n] = f2bf(o);
                } else {
                    efpbuf[(size_t)gm * 256 + (n - 256)] = f2bf(v + cst1[n]);
                }
            }
        }
    }
}

// ---------------- GEMM2k: eg_bf x Wb2t -> kfull only (bf16, LN affine) ------
__global__ __launch_bounds__(256) void gemm2k_mfma(
    const unsigned short* __restrict__ eg_bf, const unsigned short* __restrict__ Wb2t,
    const float* __restrict__ cs2, const float* __restrict__ cst2,
    const float* __restrict__ mg, const float* __restrict__ rg,
    unsigned short* __restrict__ kfull)
{
    __shared__ unsigned short As[8192], Bs[8192];
    f32x4 acc[4][4];
    int m0 = blockIdx.x * 128, n0 = blockIdx.y * 128;
    mfma_core<256>(eg_bf, Wb2t, m0, n0, As, Bs, acc);
    int lane = threadIdx.x & 63, wave = threadIdx.x >> 6;
    int wm = (wave & 1) * 64, wn = (wave >> 1) * 64;
#pragma unroll
    for (int i = 0; i < 4; i++) {
#pragma unroll
        for (int r = 0; r < 4; r++) {
            int gm = m0 + wm + i * 16 + ((lane >> 4) * 4) + r;
            float mean = mg[gm], rs = rg[gm];
#pragma unroll
            for (int j = 0; j < 4; j++) {
                int n = n0 + wn + j * 16 + (lane & 15);
                float o = rs * (acc[i][j][r] - mean * cs2[n]) + cst2[n];
                kfull[(size_t)gm * 256 + n] = f2bf(o);
            }
        }
    }
}

// ---------------- GEMM3: combined x Wot, +bo, gate by efp(bf16) -> ea -------
__global__ __launch_bounds__(256) void gemm3_mfma(
    const unsigned short* __restrict__ comb, const unsigned short* __restrict__ Wot,
    const float* __restrict__ bo, const unsigned short* __restrict__ efp,
    unsigned short* __restrict__ ea)
{
    __shared__ unsigned short As[8192], Bs[8192];
    f32x4 acc[4][4];
    int m0 = blockIdx.x * 128, n0 = blockIdx.y * 128;
    mfma_core<256>(comb, Wot, m0, n0, As, Bs, acc);
    int lane = threadIdx.x & 63, wave = threadIdx.x >> 6;
    int wm = (wave & 1) * 64, wn = (wave >> 1) * 64;
#pragma unroll
    for (int i = 0; i < 4; i++) {
#pragma unroll
        for (int r = 0; r < 4; r++) {
            int gm = m0 + wm + i * 16 + ((lane >> 4) * 4) + r;
#pragma unroll
            for (int j = 0; j < 4; j++) {
                int n = n0 + wn + j * 16 + (lane & 15);
                float o = (acc[i][j][r] + bo[n]) * bf2f(efp[(size_t)gm * 256 + n]);
                ea[(size_t)gm * 256 + n] = f2bf(o);
            }
        }
    }
}

// ---------------- GEMM4 (transposed): Woc x ea^T -> out NCHW, BN+ReLU -------
__global__ __launch_bounds__(256) void gemm4_mfma(
    const unsigned short* __restrict__ Woc, const unsigned short* __restrict__ ea,
    const float* __restrict__ scv, const float* __restrict__ shv,
    float* __restrict__ outp)
{
    __shared__ unsigned short As[8192], Bs[8192];
    f32x4 acc[4][4];
    int m0 = blockIdx.x * 128, n0 = blockIdx.y * 128;
    mfma_core<256>(Woc, ea, m0, n0, As, Bs, acc);
    int lane = threadIdx.x & 63, wave = threadIdx.x >> 6;
    int wm = (wave & 1) * 64, wn = (wave >> 1) * 64;
#pragma unroll
    for (int i = 0; i < 4; i++) {
#pragma unroll
        for (int r = 0; r < 4; r++) {
            int co = m0 + wm + i * 16 + ((lane >> 4) * 4) + r;
            float s = scv[co], hh = shv[co];
#pragma unroll
            for (int j = 0; j < 4; j++) {
                int p = n0 + wn + j * 16 + (lane & 15);
                float o = fmaxf(fmaf(acc[i][j][r], s, hh), 0.f);
                outp[((size_t)(p >> 12)) * 1048576 + (size_t)co * 4096 + (p & 4095)] = o;
            }
        }
    }
}

// ------ pool phase: blocks 0..127 k-maxpool; 128..639 weighted v-pool -------
__global__ __launch_bounds__(256) void pool_phase(
    const unsigned short* __restrict__ kfull, const float* __restrict__ eg,
    const float* __restrict__ rg, const float* __restrict__ mg,
    unsigned short* __restrict__ kpb, float* __restrict__ s1,
    float* __restrict__ s0)
{
    __shared__ float smem[4352];
    int id = blockIdx.x;
    int t = threadIdx.x;
    if (id < 128) {
        // ---- k max pool: (b, cell) ----
        int b = id >> 4, cell = id & 15;
        int hp = cell >> 2, wp = cell & 3;
        int g8 = t & 31, rr = t >> 5;
        float kmx[8];
#pragma unroll
        for (int j = 0; j < 8; j++) kmx[j] = -3.402823466e38f;
#pragma unroll
        for (int rsub = 0; rsub < 2; rsub++) {
            int r = rr * 2 + rsub;
            int prow = (hp * 16 + r) * 64 + wp * 16;
            for (int cl = 0; cl < 16; cl++) {
                size_t basei = ((size_t)(b * 4096 + prow + cl)) * 256 + g8 * 8;
                uint4 kv = *(const uint4*)(kfull + basei);
                kmx[0] = fmaxf(kmx[0], lof(kv.x)); kmx[1] = fmaxf(kmx[1], hif(kv.x));
                kmx[2] = fmaxf(kmx[2], lof(kv.y)); kmx[3] = fmaxf(kmx[3], hif(kv.y));
                kmx[4] = fmaxf(kmx[4], lof(kv.z)); kmx[5] = fmaxf(kmx[5], hif(kv.z));
                kmx[6] = fmaxf(kmx[6], lof(kv.w)); kmx[7] = fmaxf(kmx[7], hif(kv.w));
            }
        }
#pragma unroll
        for (int j = 0; j < 8; j++) smem[rr * 256 + g8 * 8 + j] = kmx[j];
        __syncthreads();
        float m = smem[t];
#pragma unroll
        for (int r2 = 1; r2 < 8; r2++) m = fmaxf(m, smem[r2 * 256 + t]);
        kpb[(size_t)(b * 16 + cell) * 256 + t] = f2bf(m);   // lossless
    } else {
        // ---- weighted v-pool partials: (b, hp, cgrp) ----
        int id2 = id - 128;
        int b = id2 >> 6, hp = (id2 >> 4) & 3, cgrp = id2 & 15;
        int rr = t >> 4, cq = t & 15, cx = cq >> 2;
        int p = (hp * 16 + rr) * 64 + cq * 4;
        float4 w4 = *(const float4*)&rg[b * 4096 + p];
        float part[16];
        const float* egb = eg + ((size_t)b * 256 + cgrp * 16) * 4096 + p;
#pragma unroll
        for (int cc = 0; cc < 16; cc++) {
            float4 v4 = *(const float4*)(egb + (size_t)cc * 4096);
            part[cc] = w4.x * v4.x + w4.y * v4.y + w4.z * v4.z + w4.w * v4.w;
        }
#pragma unroll
        for (int cc = 0; cc < 16; cc++) smem[t * 16 + cc] = part[cc];
        if (cgrp == 0) {
            float4 m4 = *(const float4*)&mg[b * 4096 + p];
            smem[4096 + t] = w4.x * m4.x + w4.y * m4.y + w4.z * m4.z + w4.w * m4.w;
        }
        __syncthreads();
        if (t < 64) {
            int cx2 = t >> 4, cc = t & 15;
            float sacc = 0.f;
#pragma unroll
            for (int rr2 = 0; rr2 < 16; rr2++)
#pragma unroll
                for (int dq = 0; dq < 4; dq++)
                    sacc += smem[(rr2 * 16 + cx2 * 4 + dq) * 16 + cc];
            s1[((size_t)(b * 16 + hp * 4 + cx2)) * 256 + cgrp * 16 + cc] = sacc;
        }
        if (cgrp == 0 && t < 4) {
            float sacc = 0.f;
#pragma unroll
            for (int rr2 = 0; rr2 < 16; rr2++)
#pragma unroll
                for (int dq = 0; dq < 4; dq++)
                    sacc += smem[4096 + rr2 * 16 + t * 4 + dq];
            s0[b * 16 + hp * 4 + t] = sacc;
        }
    }
}

// ------- v-pool mini-GEMM: vp[cell][n] from s1/s0 (fp32, exact path) --------
__global__ __launch_bounds__(256) void vpool_gemm(
    const float* __restrict__ s1, const float* __restrict__ s0,
    const float* __restrict__ lngg, const float* __restrict__ wv,
    const float* __restrict__ cs2, const float* __restrict__ cst2,
    float* __restrict__ vp)
{
    int cell = blockIdx.x;        // 0..127 = b*16+cell
    int n = threadIdx.x;
    const float* s1r = s1 + (size_t)cell * 256;
    float acc = 0.f;
    for (int c = 0; c < 256; c++)
        acc = fmaf(lngg[c] * s1r[c], wv[c * 256 + n], acc);
    vp[(size_t)cell * 256 + n] = acc * (1.f / 256.f)
        - (s0[cell] * (1.f / 256.f)) * cs2[256 + n] + cst2[256 + n];
}

// ---- combined = attn@vp + dw3x3(q): scores fused, no global attns ----------
// Block: 16 consecutive positions (same image row). Wave 0: MFMA scores ->
// softmax -> LDS. Then all 4 waves x 4 positions: a_i + depthwise conv.
__global__ __launch_bounds__(256) void combined_dw(
    const unsigned short* __restrict__ qbuf, const unsigned short* __restrict__ kpb,
    const float* __restrict__ vp, const float* __restrict__ dwt,
    unsigned short* __restrict__ combined)
{
    __shared__ float attns[256];          // 16 pos x 16 cells
    int wave = threadIdx.x >> 6, lane = threadIdx.x & 63;
    int id = blockIdx.x;                  // 2048
    int b = id & 7, seg = id >> 3;        // batch pinned per XCD
    int pidx0 = seg * 16;

    if (wave == 0) {
        int fr = lane & 15, quad = lane >> 4;
        const unsigned short* qrow = qbuf + (size_t)(b * 4096 + pidx0 + fr) * 256 + quad * 8;
        const unsigned short* krow = kpb + (size_t)(b * 16 + fr) * 256 + quad * 8;
        f32x4 sacc = {0.f, 0.f, 0.f, 0.f};
#pragma unroll
        for (int ks = 0; ks < 8; ks++) {
            bf16x8 af = *(const bf16x8*)(qrow + ks * 32);
            bf16x8 bf_ = *(const bf16x8*)(krow + ks * 32);
            sacc = __builtin_amdgcn_mfma_f32_16x16x32_bf16(af, bf_, sacc, 0, 0, 0);
        }
#pragma unroll
        for (int r = 0; r < 4; r++) {
            float s = sacc[r] * 0.0625f;  // HID^-0.5
            float mx = s;
#pragma unroll
            for (int off = 8; off >= 1; off >>= 1) mx = fmaxf(mx, __shfl_xor(mx, off));
            float e = __expf(s - mx);
            float sum = e;
#pragma unroll
            for (int off = 8; off >= 1; off >>= 1) sum += __shfl_xor(sum, off);
            attns[(quad * 4 + r) * 16 + fr] = e / sum;
        }
    }
    __syncthreads();

    int pidx = pidx0 + wave * 4;
    int h = pidx >> 6, w0 = pidx & 63;
    int o4 = lane * 4;

    float4 kreg[9];
#pragma unroll
    for (int tap = 0; tap < 9; tap++)
        kreg[tap] = *(const float4*)&dwt[tap * 256 + o4];

    float4 acc[4];
#pragma unroll
    for (int i = 0; i < 4; i++) acc[i] = (float4){0.f, 0.f, 0.f, 0.f};

    const float* arow = attns + (wave * 4) * 16;
#pragma unroll
    for (int c = 0; c < 16; c++) {
        float4 v = *(const float4*)&vp[(size_t)(b * 16 + c) * 256 + o4];
#pragma unroll
        for (int i = 0; i < 4; i++) {
            float a = arow[i * 16 + c];
            acc[i].x = fmaf(a, v.x, acc[i].x); acc[i].y = fmaf(a, v.y, acc[i].y);
            acc[i].z = fmaf(a, v.z, acc[i].z); acc[i].w = fmaf(a, v.w, acc[i].w);
        }
    }
#pragma unroll
    for (int dy = 0; dy < 3; dy++) {
        int hh = h + dy - 1;
        if (hh < 0 || hh > 63) continue;
        const unsigned short* qr = qbuf + ((size_t)(b * 4096 + hh * 64)) * 256;
        float4 ft[6];
#pragma unroll
        for (int c = 0; c < 6; c++) {
            int xx = w0 - 1 + c;
            if (xx < 0 || xx > 63) {
                ft[c] = (float4){0.f, 0.f, 0.f, 0.f};
            } else {
                uint2 qa = *(const uint2*)(qr + (size_t)xx * 256 + o4);
                ft[c] = (float4){lof(qa.x), hif(qa.x), lof(qa.y), hif(qa.y)};
            }
        }
#pragma unroll
        for (int dx = 0; dx < 3; dx++) {
            float4 kk = kreg[dy * 3 + dx];
#pragma unroll
            for (int i = 0; i < 4; i++) {
                float4 qv = ft[i + dx];
                acc[i].x = fmaf(qv.x, kk.x, acc[i].x);
                acc[i].y = fmaf(qv.y, kk.y, acc[i].y);
                acc[i].z = fmaf(qv.z, kk.z, acc[i].z);
                acc[i].w = fmaf(qv.w, kk.w, acc[i].w);
            }
        }
    }
#pragma unroll
    for (int i = 0; i < 4; i++) {
        uint2 pk;
        pk.x = (unsigned)f2bf(acc[i].x) | ((unsigned)f2bf(acc[i].y) << 16);
        pk.y = (unsigned)f2bf(acc[i].z) | ((unsigned)f2bf(acc[i].w) << 16);
        *(uint2*)(combined + ((size_t)(b * 4096 + pidx + i)) * 256 + o4) = pk;
    }
}

// ---------------------------------------------------------------------------
extern "C" void kernel_launch(void* const* d_in, const int* in_sizes, int n_in,
                              void* d_out, int out_size, void* d_ws, size_t ws_size,
                              hipStream_t stream)
{
    const float* e_f   = (const float*)d_in[0];
    const float* e_g   = (const float*)d_in[1];
    const float* lnfg  = (const float*)d_in[4];
    const float* lnfb  = (const float*)d_in[5];
    const float* lngg  = (const float*)d_in[6];
    const float* lngb  = (const float*)d_in[7];
    const float* wq    = (const float*)d_in[8];
    const float* bq    = (const float*)d_in[9];
    const float* wk    = (const float*)d_in[10];
    const float* bk    = (const float*)d_in[11];
    const float* wv    = (const float*)d_in[12];
    const float* bv    = (const float*)d_in[13];
    const float* wo    = (const float*)d_in[14];
    const float* bo    = (const float*)d_in[15];
    const float* dwk   = (const float*)d_in[16];
    const float* efpw  = (const float*)d_in[17];
    const float* efpb  = (const float*)d_in[18];
    const float* outcw = (const float*)d_in[19];
    const float* outcb = (const float*)d_in[20];
    const float* bng   = (const float*)d_in[21];
    const float* bnb   = (const float*)d_in[22];
    const float* bnm   = (const float*)d_in[23];
    const float* bnv   = (const float*)d_in[24];
    float* outp = (float*)d_out;

    char* base = (char*)d_ws;
    auto alloc = [&](size_t bytes) -> char* {
        char* r = base; base += (bytes + 255) & ~(size_t)255; return r;
    };
    float* pf    = (float*)alloc(8 * 32768 * 4);
    float* pfq   = (float*)alloc(8 * 32768 * 4);
    float* pg    = (float*)alloc(4 * 32768 * 4);
    float* pgq   = (float*)alloc(4 * 32768 * 4);
    float* mf    = (float*)alloc(32768 * 4);
    float* rf    = (float*)alloc(32768 * 4);
    float* mg    = (float*)alloc(32768 * 4);
    float* rg    = (float*)alloc(32768 * 4);
    float* cs1   = (float*)alloc(512 * 4);
    float* cst1  = (float*)alloc(512 * 4);
    float* cs2   = (float*)alloc(512 * 4);
    float* cst2  = (float*)alloc(512 * 4);
    float* scv   = (float*)alloc(256 * 4);
    float* shv   = (float*)alloc(256 * 4);
    float* dwt   = (float*)alloc(9 * 256 * 4);
    unsigned short* Wb1t = (unsigned short*)alloc(262144 * 2);
    unsigned short* Wb2t = (unsigned short*)alloc(65536 * 2);
    unsigned short* Wot  = (unsigned short*)alloc(65536 * 2);
    unsigned short* Woc  = (unsigned short*)alloc(65536 * 2);
    unsigned short* ef_bf = (unsigned short*)alloc((size_t)32768 * 512 * 2);
    unsigned short* eg_bf = (unsigned short*)alloc((size_t)32768 * 256 * 2);
    unsigned short* qbuf  = (unsigned short*)alloc((size_t)32768 * 256 * 2);
    unsigned short* efpbuf = (unsigned short*)alloc((size_t)32768 * 256 * 2);
    unsigned short* kfull = (unsigned short*)alloc((size_t)32768 * 256 * 2); // -> combined
    unsigned short* ea    = (unsigned short*)alloc((size_t)32768 * 256 * 2);
    unsigned short* kpb  = (unsigned short*)alloc(128 * 256 * 2);
    float* vp    = (float*)alloc(128 * 256 * 4);
    float* s1    = (float*)alloc(128 * 256 * 4);
    float* s0    = (float*)alloc(128 * 4);

    prep_all<<<1806, 256, 0, stream>>>(
        lnfg, lnfb, wq, bq, efpw, efpb, lngg, lngb, wk, bk, wv, bv, wo,
        outcw, outcb, bng, bnb, bnm, bnv, dwk,
        Wb1t, Wb2t, Wot, Woc, dwt, cs1, cst1, cs2, cst2, scv, shv);
    transpose_fg<<<6144, 256, 0, stream>>>(e_f, e_g, ef_bf, eg_bf,
                                           pf, pfq, pg, pgq);
    ln_finalize<<<128, 256, 0, stream>>>(pf, pfq, pg, pgq, mf, rf, mg, rg);
    gemm1_mfma<<<dim3(256, 4), 256, 0, stream>>>(ef_bf, Wb1t, cs1, cst1, mf, rf,
                                                 qbuf, efpbuf);
    gemm2k_mfma<<<dim3(256, 2), 256, 0, stream>>>(eg_bf, Wb2t, cs2, cst2, mg, rg,
                                                  kfull);
    pool_phase<<<640, 256, 0, stream>>>(kfull, e_g, rg, mg, kpb, s1, s0);
    vpool_gemm<<<128, 256, 0, stream>>>(s1, s0, lngg, wv, cs2, cst2, vp);
    combined_dw<<<2048, 256, 0, stream>>>(qbuf, kpb, vp, dwt, /*combined=*/kfull);
    gemm3_mfma<<<dim3(256, 2), 256, 0, stream>>>(/*combined=*/kfull, Wot, bo,
                                                 efpbuf, /*ea=*/ea);
    gemm4_mfma<<<dim3(2, 256), 256, 0, stream>>>(Woc, ea, scv, shv, outp);
}